// Round 7
// baseline (574.827 us; speedup 1.0000x reference)
//
#include <hip/hip_runtime.h>
#include <hip/hip_cooperative_groups.h>
#include <math.h>

namespace cg = cooperative_groups;

#define NN 50000
#define NE 800000
#define NG 64

// ---------------- ws layout (float offsets) ----------------
#define WS_C     0                       // 8 floats: [h*4 + {att.Wl, att.Wr, att.We, att.B}]
#define WS_ACC   16                      // 4*NN floats: {den0,den1,t10,t11} per node (float4)
#define WS_BNSUM (WS_ACC + 4*NN)         // 128 (fallback path)  -- coop path: WS_MOM overlaps
#define WS_BNSQ  (WS_BNSUM + 128)        // 128 (fallback path)
#define WS_MOM   WS_BNSUM                // 14 floats: S1..S4, M11,M12,M13,M14,M22,M23,M24,M33,M34,M44
#define WS_HEAD  (WS_BNSQ + 128)         // 4*NN u32 chain heads (0xFFFFFFFF = end)
#define WS_PREV  (WS_HEAD + 4*NN)        // NE u32 next-pointers
#define WS_STAGE (WS_PREV + NE)          // NE float4 = {e0, e1, e0*xs, e1*xs}
#define WS_END   (WS_STAGE + 4*NE)
#define WS_NEED_BYTES ((size_t)WS_END * 4 + 256)

#define LEND 0xFFFFFFFFu
#define NQ (NE / 4)

static_assert(((WS_STAGE * 4) % 16) == 0, "stage 16B alignment");
static_assert(NE % 4 == 0, "edge unroll");

// ---------------- shared score machinery ----------------
#define STEP(wl_, wr_, we_, bb_, at_, xs_, xd_, ae_, acc_)                 \
  { float tt = fmaf(we_, ae_, bb_); tt = fmaf(wr_, xd_, tt);               \
    tt = fmaf(wl_, xs_, tt); acc_ = fmaf(fabsf(tt), at_, acc_); }

#define STEP4(c, q0, q1, q2, q3)                                           \
  STEP(wl.c, wr.c, we.c, bb.c, at.c, xs0, xd0, ae0, q0)                    \
  STEP(wl.c, wr.c, we.c, bb.c, at.c, xs1, xd1, ae1, q1)                    \
  STEP(wl.c, wr.c, we.c, bb.c, at.c, xs2, xd2, ae2, q2)                    \
  STEP(wl.c, wr.c, we.c, bb.c, at.c, xs3, xd3, ae3, q3)

#define SCORE_CORE                                                         \
  int4 s4 = *(const int4*)&ei[base];                                       \
  int4 dd4 = *(const int4*)&ei[NE + base];                                 \
  float4 ae4 = *(const float4*)&eattr[base];                               \
  float xs0 = x[s4.x], xs1 = x[s4.y], xs2 = x[s4.z], xs3 = x[s4.w];        \
  float xd0 = x[dd4.x], xd1 = x[dd4.y], xd2 = x[dd4.z], xd3 = x[dd4.w];    \
  float ae0 = ae4.x, ae1 = ae4.y, ae2 = ae4.z, ae3 = ae4.w;

#define SCORE_LOOPS                                                        \
  float a00 = 0.f, a01 = 0.f, a02 = 0.f, a03 = 0.f;                        \
  float a10 = 0.f, a11 = 0.f, a12 = 0.f, a13 = 0.f;                        \
  _Pragma("unroll 2")                                                      \
  for (int j = 0; j < 128; j += 4) {                                       \
    float4 wl = *(const float4*)&sWl[j];                                   \
    float4 wr = *(const float4*)&sWr[j];                                   \
    float4 we = *(const float4*)&sWe[j];                                   \
    float4 bb = *(const float4*)&sB[j];                                    \
    float4 at = *(const float4*)&sAt[j];                                   \
    STEP4(x, a00, a01, a02, a03)                                           \
    STEP4(y, a00, a01, a02, a03)                                           \
    STEP4(z, a00, a01, a02, a03)                                           \
    STEP4(w, a00, a01, a02, a03)                                           \
  }                                                                        \
  _Pragma("unroll 2")                                                      \
  for (int j = 128; j < 256; j += 4) {                                     \
    float4 wl = *(const float4*)&sWl[j];                                   \
    float4 wr = *(const float4*)&sWr[j];                                   \
    float4 we = *(const float4*)&sWe[j];                                   \
    float4 bb = *(const float4*)&sB[j];                                    \
    float4 at = *(const float4*)&sAt[j];                                   \
    STEP4(x, a10, a11, a12, a13)                                           \
    STEP4(y, a10, a11, a12, a13)                                           \
    STEP4(z, a10, a11, a12, a13)                                           \
    STEP4(w, a10, a11, a12, a13)                                           \
  }                                                                        \
  float4 c0 = *(const float4*)&ws[WS_C];                                   \
  float4 c1 = *(const float4*)&ws[WS_C + 4];

#define SMEM_WEIGHTS_DECL                                                  \
  __shared__ __align__(16) float sWl[256], sWr[256], sWe[256], sB[256], sAt[256];

#define SMEM_WEIGHTS_LOAD                                                  \
  { int t = threadIdx.x;                                                   \
    sWl[t] = Wl[t]; sWr[t] = Wr[t]; sWe[t] = We[t];                        \
    sB[t] = bl[t] + br[t]; sAt[t] = att[t]; }                              \
  __syncthreads();

#define SCORES(xs_, xd_, ae_, accA, accB, out0, out1)                      \
  { float lin0 = fmaf(c0.x, xs_, fmaf(c0.y, xd_, fmaf(c0.z, ae_, c0.w))); \
    out0 = fmaf(0.4f, accA, 0.6f * lin0);                                  \
    float lin1 = fmaf(c1.x, xs_, fmaf(c1.y, xd_, fmaf(c1.z, ae_, c1.w))); \
    out1 = fmaf(0.4f, accB, 0.6f * lin1); }

// ==================== cooperative mega-kernel ====================
extern "C" __global__ __launch_bounds__(256, 4)
void kmega(const int* __restrict__ ei, const float* __restrict__ x,
           const float* __restrict__ eattr, const int* __restrict__ batch,
           const float* __restrict__ Wl, const float* __restrict__ bl,
           const float* __restrict__ Wr, const float* __restrict__ br,
           const float* __restrict__ We, const float* __restrict__ att,
           const float* __restrict__ bias, const float* __restrict__ gamma,
           const float* __restrict__ beta,
           float* __restrict__ ws, float* __restrict__ out)
{
  cg::grid_group grid = cg::this_grid();
  SMEM_WEIGHTS_DECL
  __shared__ float red[4][256];      // block-0 C reduce
  __shared__ float smom[56];         // 4 waves x 14 moment partials
  __shared__ float pool[4][128];     // pool slots
  SMEM_WEIGHTS_LOAD

  const int t = threadIdx.x;
  const int gtid = blockIdx.x * 256 + t;
  const int gsz = gridDim.x * 256;

  // ---- phase 1: init heads / moments / out; block 0 computes C ----
  {
    unsigned* head = (unsigned*)(ws + WS_HEAD);
    for (int i = gtid; i < 4 * NN; i += gsz) head[i] = LEND;
    for (int i = gtid; i < 14; i += gsz) ws[WS_MOM + i] = 0.f;
    for (int i = gtid; i < NG * 128; i += gsz) out[i] = 0.f;
    if (blockIdx.x == 0) {
      float a = sAt[t];
      red[0][t] = a * sWl[t];
      red[1][t] = a * sWr[t];
      red[2][t] = a * sWe[t];
      red[3][t] = a * sB[t];
      __syncthreads();
      if (t < 8) {
        int k = t >> 1, h = t & 1;
        float s = 0.f;
        for (int d = 0; d < 128; ++d) s += red[k][h * 128 + d];
        ws[WS_C + h * 4 + k] = s;
      }
    }
  }
  grid.sync();

  // ---- phase 2: edges — score, exp, 4-chain linked-list staging ----
  {
    unsigned* head = (unsigned*)(ws + WS_HEAD);
    float4* stage = (float4*)(ws + WS_STAGE);
    unsigned* prev = (unsigned*)(ws + WS_PREV);
    for (int q = gtid; q < NQ; q += gsz) {
      int base = q * 4;
      SCORE_CORE
      unsigned pv0 = atomicExch(&head[4 * dd4.x + 0], (unsigned)(base + 0));
      unsigned pv1 = atomicExch(&head[4 * dd4.y + 1], (unsigned)(base + 1));
      unsigned pv2 = atomicExch(&head[4 * dd4.z + 2], (unsigned)(base + 2));
      unsigned pv3 = atomicExch(&head[4 * dd4.w + 3], (unsigned)(base + 3));
      SCORE_LOOPS
      float s0, s1;
      float4 pay0, pay1, pay2, pay3;
#define PAY(xs_, xd_, ae_, accA, accB, pp)                                 \
      { SCORES(xs_, xd_, ae_, accA, accB, s0, s1)                          \
        float e0 = __expf(s0), e1 = __expf(s1);                            \
        pp = make_float4(e0, e1, e0 * xs_, e1 * xs_); }
      PAY(xs0, xd0, ae0, a00, a10, pay0)
      PAY(xs1, xd1, ae1, a01, a11, pay1)
      PAY(xs2, xd2, ae2, a02, a12, pay2)
      PAY(xs3, xd3, ae3, a03, a13, pay3)
#undef PAY
      stage[base + 0] = pay0;
      stage[base + 1] = pay1;
      stage[base + 2] = pay2;
      stage[base + 3] = pay3;
      *(uint4*)&prev[base] = make_uint4(pv0, pv1, pv2, pv3);
    }
  }
  grid.sync();

  // ---- phase 3: gather (chain walk) + 14-moment reduction ----
  {
    const unsigned* head = (const unsigned*)(ws + WS_HEAD);
    const unsigned* prev = (const unsigned*)(ws + WS_PREV);
    const float4* stage = (const float4*)(ws + WS_STAGE);
    float f1 = 0.f, f2 = 0.f, f3 = 0.f, f4 = 0.f;
    for (int n = gtid; n < NN; n += gsz) {
      uint4 p = *(const uint4*)&head[4 * n];
      float4 A0 = make_float4(0.f, 0.f, 0.f, 0.f);
      float4 A1 = A0, A2 = A0, A3 = A0;
      while ((p.x & p.y & p.z & p.w) != LEND) {
#define HOP(pc, Ac)                                                        \
        if (pc != LEND) {                                                  \
          float4 qq = stage[pc];                                           \
          unsigned np = prev[pc];                                          \
          Ac.x += qq.x; Ac.y += qq.y; Ac.z += qq.z; Ac.w += qq.w;          \
          pc = np;                                                         \
        }
        HOP(p.x, A0) HOP(p.y, A1) HOP(p.z, A2) HOP(p.w, A3)
#undef HOP
      }
      float den0 = (A0.x + A1.x) + (A2.x + A3.x);
      float den1 = (A0.y + A1.y) + (A2.y + A3.y);
      float t10  = (A0.z + A1.z) + (A2.z + A3.z);
      float t11  = (A0.w + A1.w) + (A2.w + A3.w);
      *(float4*)&ws[WS_ACC + 4 * n] = make_float4(den0, den1, t10, t11);
      float r0 = 1.f / (den0 + 1e-16f);
      float r1 = 1.f / (den1 + 1e-16f);
      f1 += den0 * r0; f2 += t10 * r0; f3 += den1 * r1; f4 += t11 * r1;
    }
    // moments: S1..S4, M11,M12,M13,M14,M22,M23,M24,M33,M34,M44
    float pm[14] = { f1, f2, f3, f4,
                     f1*f1, f1*f2, f1*f3, f1*f4,
                     f2*f2, f2*f3, f2*f4,
                     f3*f3, f3*f4, f4*f4 };
    // NOTE: with <=1 node per thread (gsz >= NN per stride? not guaranteed)
    // products of summed f are only valid when each thread sees <=1 node.
    // gsz = 262144 > NN so the loop body executes at most once per thread.
#pragma unroll
    for (int k = 0; k < 14; ++k) {
      float v = pm[k];
#pragma unroll
      for (int m = 32; m >= 1; m >>= 1) v += __shfl_xor(v, m);
      pm[k] = v;
    }
    int wid = t >> 6, lane = t & 63;
    if (lane == 0) {
#pragma unroll
      for (int k = 0; k < 14; ++k) smom[wid * 14 + k] = pm[k];
    }
    __syncthreads();
    if (t < 14) {
      float s = smom[t] + smom[14 + t] + smom[28 + t] + smom[42 + t];
      if (s != 0.f) atomicAdd(&ws[WS_MOM + t], s);
    }
  }
  grid.sync();

  // ---- phase 4: BN from moments + leaky_relu + graph pooling ----
  {
    const int CHUNK = (NN + (int)gridDim.x - 1) / (int)gridDim.x;
    int n0 = blockIdx.x * CHUNK;
    if (n0 < NN) {
      int n1 = n0 + CHUNK; if (n1 > NN) n1 = NN;
      int d = t & 127;
      int row = t >> 7;
      float S1 = ws[WS_MOM + 0], S2 = ws[WS_MOM + 1];
      float S3 = ws[WS_MOM + 2], S4 = ws[WS_MOM + 3];
      float M11 = ws[WS_MOM + 4], M12 = ws[WS_MOM + 5], M13 = ws[WS_MOM + 6];
      float M14 = ws[WS_MOM + 7], M22 = ws[WS_MOM + 8], M23 = ws[WS_MOM + 9];
      float M24 = ws[WS_MOM + 10], M33 = ws[WS_MOM + 11], M34 = ws[WS_MOM + 12];
      float M44 = ws[WS_MOM + 13];
      float g1 = 0.5f * bl[d], g2 = 0.5f * Wl[d];
      float g3 = 0.5f * bl[128 + d], g4 = 0.5f * Wl[128 + d];
      float g5 = bias[d];
      const float invN = 1.f / (float)NN;
      float dotS = g1 * S1 + g2 * S2 + g3 * S3 + g4 * S4;
      float mean = (dotS + (float)NN * g5) * invN;
      float sumsq = g1*g1*M11 + g2*g2*M22 + g3*g3*M33 + g4*g4*M44
                  + 2.f*(g1*g2*M12 + g1*g3*M13 + g1*g4*M14
                       + g2*g3*M23 + g2*g4*M24 + g3*g4*M34)
                  + 2.f*g5*dotS + (float)NN*g5*g5;
      float var = fmaf(sumsq, invN, -mean * mean);
      float scale = gamma[d] * rsqrtf(var + 1e-5f);
      float shift = fmaf(-mean, scale, beta[d]);
      for (int i = t; i < 512; i += 256) ((float*)pool)[i] = 0.f;
      __syncthreads();
      int g0 = batch[n0];
      for (int n = n0 + row; n < n1; n += 2) {
        float4 a = *(const float4*)&ws[WS_ACC + 4 * n];
        float r0 = 1.f / (a.x + 1e-16f);
        float r1 = 1.f / (a.y + 1e-16f);
        float o = g1 * (a.x * r0) + g2 * (a.z * r0)
                + g3 * (a.y * r1) + g4 * (a.w * r1) + g5;
        float v = fmaf(o, scale, shift);
        v = v > 0.f ? v : 0.01f * v;
        int g = batch[n];
        int slot = g - g0;
        if (slot < 4) atomicAdd(&pool[slot][d], v);
        else atomicAdd(&out[g * 128 + d], v);
      }
      __syncthreads();
      for (int i = t; i < 512; i += 256) {
        int slot = i >> 7, dd = i & 127;
        int g = g0 + slot;
        float v = pool[slot][dd];
        if (g < NG && v != 0.f) atomicAdd(&out[g * 128 + dd], v);
      }
    }
  }
}

// ==================== fallback multi-kernel path (R6) ====================
extern "C" __global__ __launch_bounds__(256)
void k0_init(float* __restrict__ ws,
             const float* __restrict__ att, const float* __restrict__ Wl,
             const float* __restrict__ Wr, const float* __restrict__ We,
             const float* __restrict__ bl, const float* __restrict__ br,
             float* __restrict__ out, int dense)
{
  int tid = blockIdx.x * 256 + threadIdx.x;
  int nt = gridDim.x * 256;
  if (dense) {
    unsigned* head = (unsigned*)(ws + WS_HEAD);
    for (int i = tid; i < 4 * NN; i += nt) head[i] = LEND;
  } else {
    for (int i = tid; i < 4 * NN; i += nt) ws[WS_ACC + i] = 0.f;
  }
  for (int i = tid; i < 256; i += nt) ws[WS_BNSUM + i] = 0.f;
  for (int i = tid; i < NG * 128; i += nt) out[i] = 0.f;
  if (blockIdx.x == 0) {
    __shared__ float red[4][256];
    int t = threadIdx.x;
    float a = att[t];
    red[0][t] = a * Wl[t];
    red[1][t] = a * Wr[t];
    red[2][t] = a * We[t];
    red[3][t] = a * (bl[t] + br[t]);
    __syncthreads();
    if (t < 8) {
      int k = t >> 1, h = t & 1;
      float s = 0.f;
      for (int d = 0; d < 128; ++d) s += red[k][h * 128 + d];
      ws[WS_C + h * 4 + k] = s;
    }
  }
}

extern "C" __global__ __launch_bounds__(256)
void ke_edge(const int* __restrict__ ei, const float* __restrict__ x,
             const float* __restrict__ eattr,
             const float* __restrict__ Wl, const float* __restrict__ Wr,
             const float* __restrict__ We, const float* __restrict__ bl,
             const float* __restrict__ br, const float* __restrict__ att,
             float* __restrict__ ws)
{
  SMEM_WEIGHTS_DECL
  SMEM_WEIGHTS_LOAD
  int base = (blockIdx.x * 256 + threadIdx.x) * 4;
  if (base >= NE) return;
  SCORE_CORE
  unsigned* head = (unsigned*)(ws + WS_HEAD);
  unsigned pv0 = atomicExch(&head[4 * dd4.x + 0], (unsigned)(base + 0));
  unsigned pv1 = atomicExch(&head[4 * dd4.y + 1], (unsigned)(base + 1));
  unsigned pv2 = atomicExch(&head[4 * dd4.z + 2], (unsigned)(base + 2));
  unsigned pv3 = atomicExch(&head[4 * dd4.w + 3], (unsigned)(base + 3));
  SCORE_LOOPS
  float4* stage = (float4*)(ws + WS_STAGE);
  unsigned* prev = (unsigned*)(ws + WS_PREV);
  float s0, s1;
  float4 pay0, pay1, pay2, pay3;
#define PAY(xs_, xd_, ae_, accA, accB, pp)                                 \
  { SCORES(xs_, xd_, ae_, accA, accB, s0, s1)                              \
    float e0 = __expf(s0), e1 = __expf(s1);                                \
    pp = make_float4(e0, e1, e0 * xs_, e1 * xs_); }
  PAY(xs0, xd0, ae0, a00, a10, pay0)
  PAY(xs1, xd1, ae1, a01, a11, pay1)
  PAY(xs2, xd2, ae2, a02, a12, pay2)
  PAY(xs3, xd3, ae3, a03, a13, pay3)
#undef PAY
  stage[base + 0] = pay0;
  stage[base + 1] = pay1;
  stage[base + 2] = pay2;
  stage[base + 3] = pay3;
  *(uint4*)&prev[base] = make_uint4(pv0, pv1, pv2, pv3);
}

extern "C" __global__ __launch_bounds__(256)
void kf_gather(float* __restrict__ ws)
{
  int n = blockIdx.x * 256 + threadIdx.x;
  if (n >= NN) return;
  const unsigned* head = (const unsigned*)(ws + WS_HEAD);
  const unsigned* prev = (const unsigned*)(ws + WS_PREV);
  const float4* stage = (const float4*)(ws + WS_STAGE);
  uint4 p = *(const uint4*)&head[4 * n];
  float4 A0 = make_float4(0.f, 0.f, 0.f, 0.f);
  float4 A1 = A0, A2 = A0, A3 = A0;
  while ((p.x & p.y & p.z & p.w) != LEND) {
#define HOP(pc, Ac)                                                        \
    if (pc != LEND) {                                                      \
      float4 q = stage[pc];                                                \
      unsigned np = prev[pc];                                              \
      Ac.x += q.x; Ac.y += q.y; Ac.z += q.z; Ac.w += q.w;                  \
      pc = np;                                                             \
    }
    HOP(p.x, A0) HOP(p.y, A1) HOP(p.z, A2) HOP(p.w, A3)
#undef HOP
  }
  float4 r;
  r.x = (A0.x + A1.x) + (A2.x + A3.x);
  r.y = (A0.y + A1.y) + (A2.y + A3.y);
  r.z = (A0.z + A1.z) + (A2.z + A3.z);
  r.w = (A0.w + A1.w) + (A2.w + A3.w);
  *(float4*)&ws[WS_ACC + 4 * n] = r;
}

extern "C" __global__ __launch_bounds__(256)
void k12f(const int* __restrict__ ei, const float* __restrict__ x,
          const float* __restrict__ eattr,
          const float* __restrict__ Wl, const float* __restrict__ Wr,
          const float* __restrict__ We, const float* __restrict__ bl,
          const float* __restrict__ br, const float* __restrict__ att,
          float* __restrict__ ws)
{
  SMEM_WEIGHTS_DECL
  SMEM_WEIGHTS_LOAD
  int base = (blockIdx.x * 256 + threadIdx.x) * 4;
  if (base >= NE) return;
  SCORE_CORE
  SCORE_LOOPS
  float* acc = ws + WS_ACC;
  float s0, s1;
#define EPI2(xs_, xd_, ae_, accA, accB, dsti)                              \
  { SCORES(xs_, xd_, ae_, accA, accB, s0, s1)                              \
    float e0 = __expf(s0), e1 = __expf(s1);                                \
    float* a = &acc[4 * dsti];                                             \
    atomicAdd(a + 0, e0); atomicAdd(a + 1, e1);                            \
    atomicAdd(a + 2, e0 * xs_); atomicAdd(a + 3, e1 * xs_); }
  EPI2(xs0, xd0, ae0, a00, a10, dd4.x)
  EPI2(xs1, xd1, ae1, a01, a11, dd4.y)
  EPI2(xs2, xd2, ae2, a02, a12, dd4.z)
  EPI2(xs3, xd3, ae3, a03, a13, dd4.w)
#undef EPI2
}

__device__ __forceinline__ float node_out4(float4 a, float wl0, float wl1,
                                           float b0, float b1, float bs)
{
  float r0 = 1.f / (a.x + 1e-16f);
  float r1 = 1.f / (a.y + 1e-16f);
  return 0.5f * (fmaf(wl0, a.z * r0, b0 * (a.x * r0)) +
                 fmaf(wl1, a.w * r1, b1 * (a.y * r1))) + bs;
}

extern "C" __global__ __launch_bounds__(256)
void k3_stats(const float* __restrict__ Wl, const float* __restrict__ bl,
              const float* __restrict__ bias, float* __restrict__ ws)
{
  int d = threadIdx.x & 127;
  int row = threadIdx.x >> 7;
  float wl0 = Wl[d], wl1 = Wl[128 + d];
  float b0 = bl[d], b1 = bl[128 + d];
  float bs = bias[d];
  float sum = 0.f, sq = 0.f;
  for (int n = blockIdx.x * 2 + row; n < NN; n += gridDim.x * 2) {
    float4 a = *(const float4*)&ws[WS_ACC + 4 * n];
    float o = node_out4(a, wl0, wl1, b0, b1, bs);
    sum += o;
    sq = fmaf(o, o, sq);
  }
  __shared__ float l1[256], l2[256];
  l1[threadIdx.x] = sum; l2[threadIdx.x] = sq;
  __syncthreads();
  if (row == 0) {
    atomicAdd(&ws[WS_BNSUM + d], l1[d] + l1[128 + d]);
    atomicAdd(&ws[WS_BNSQ + d], l2[d] + l2[128 + d]);
  }
}

extern "C" __global__ __launch_bounds__(256)
void k4_pool(const int* __restrict__ batch,
             const float* __restrict__ Wl, const float* __restrict__ bl,
             const float* __restrict__ bias, const float* __restrict__ gamma,
             const float* __restrict__ beta,
             float* __restrict__ ws, float* __restrict__ out)
{
  const int CHUNK = (NN + (int)gridDim.x - 1) / (int)gridDim.x;
  int n0 = blockIdx.x * CHUNK;
  if (n0 >= NN) return;
  int n1 = n0 + CHUNK; if (n1 > NN) n1 = NN;
  int d = threadIdx.x & 127;
  int row = threadIdx.x >> 7;
  const float invN = 1.f / (float)NN;
  float mean = ws[WS_BNSUM + d] * invN;
  float var = fmaf(ws[WS_BNSQ + d], invN, -mean * mean);
  float scale = gamma[d] * rsqrtf(var + 1e-5f);
  float shift = fmaf(-mean, scale, beta[d]);
  float wl0 = Wl[d], wl1 = Wl[128 + d];
  float b0 = bl[d], b1 = bl[128 + d];
  float bs = bias[d];
  __shared__ float pool[4][128];
  for (int i = threadIdx.x; i < 512; i += 256) ((float*)pool)[i] = 0.f;
  __syncthreads();
  int g0 = batch[n0];
  for (int n = n0 + row; n < n1; n += 2) {
    float4 a = *(const float4*)&ws[WS_ACC + 4 * n];
    float o = node_out4(a, wl0, wl1, b0, b1, bs);
    float v = fmaf(o, scale, shift);
    v = v > 0.f ? v : 0.01f * v;
    int g = batch[n];
    int slot = g - g0;
    if (slot < 4) atomicAdd(&pool[slot][d], v);
    else atomicAdd(&out[g * 128 + d], v);
  }
  __syncthreads();
  for (int i = threadIdx.x; i < 512; i += 256) {
    int slot = i >> 7, dd = i & 127;
    int g = g0 + slot;
    float v = pool[slot][dd];
    if (g < NG && v != 0.f) atomicAdd(&out[g * 128 + dd], v);
  }
}

extern "C" void kernel_launch(void* const* d_in, const int* in_sizes, int n_in,
                              void* d_out, int out_size, void* d_ws, size_t ws_size,
                              hipStream_t stream) {
  const float* x     = (const float*)d_in[0];
  const int*   ei    = (const int*)d_in[1];
  const float* eattr = (const float*)d_in[2];
  const int*   batch = (const int*)d_in[3];
  const float* Wl    = (const float*)d_in[4];
  const float* bl    = (const float*)d_in[5];
  const float* Wr    = (const float*)d_in[6];
  const float* br    = (const float*)d_in[7];
  const float* We    = (const float*)d_in[8];
  const float* att   = (const float*)d_in[9];
  const float* bias  = (const float*)d_in[10];
  const float* gam   = (const float*)d_in[11];
  const float* bet   = (const float*)d_in[12];
  float* ws  = (float*)d_ws;
  float* out = (float*)d_out;

  const bool dense = (ws_size >= WS_NEED_BYTES);
  const int EB = (NE / 4 + 255) / 256;

  bool done = false;
  if (dense) {
    void* kargs[] = { (void*)&ei, (void*)&x, (void*)&eattr, (void*)&batch,
                      (void*)&Wl, (void*)&bl, (void*)&Wr, (void*)&br,
                      (void*)&We, (void*)&att, (void*)&bias, (void*)&gam,
                      (void*)&bet, (void*)&ws, (void*)&out };
    hipError_t e = hipLaunchCooperativeKernel((const void*)kmega,
                                              dim3(1024), dim3(256),
                                              kargs, 0, stream);
    if (e == hipSuccess) done = true;
    else (void)hipGetLastError();   // clear, fall back
  }
  if (!done) {
    hipLaunchKernelGGL(k0_init, dim3(128), dim3(256), 0, stream,
                       ws, att, Wl, Wr, We, bl, br, out, dense ? 1 : 0);
    if (dense) {
      hipLaunchKernelGGL(ke_edge, dim3(EB), dim3(256), 0, stream,
                         ei, x, eattr, Wl, Wr, We, bl, br, att, ws);
      hipLaunchKernelGGL(kf_gather, dim3((NN + 255) / 256), dim3(256), 0, stream, ws);
    } else {
      hipLaunchKernelGGL(k12f, dim3(EB), dim3(256), 0, stream,
                         ei, x, eattr, Wl, Wr, We, bl, br, att, ws);
    }
    hipLaunchKernelGGL(k3_stats, dim3(256), dim3(256), 0, stream,
                       Wl, bl, bias, ws);
    hipLaunchKernelGGL(k4_pool, dim3(256), dim3(256), 0, stream,
                       batch, Wl, bl, bias, gam, bet, ws, out);
  }
}

// Round 8
// 373.214 us; speedup vs baseline: 1.5402x; 1.5402x over previous
//
#include <hip/hip_runtime.h>
#include <math.h>

#define NN 50000
#define NE 800000
#define NG 64

// ---------------- ws layout (float offsets) ----------------
#define WS_C     0                       // 8 floats: [h*4 + {att.Wl, att.Wr, att.We, att.B}]
#define WS_ACC   16                      // 4*NN floats: {den0,den1,t10,t11} per node (float4)
#define WS_BNSUM (WS_ACC + 4*NN)         // 128 (fallback path)
#define WS_BNSQ  (WS_BNSUM + 128)        // 128 (fallback path)
#define WS_MOM   WS_BNSUM                // dense path: 14 floats (overlaps BNSUM, paths exclusive)
#define WS_HEAD  (WS_BNSQ + 128)         // 4*NN u32 chain heads (0xFFFFFFFF = end)
#define WS_PREV  (WS_HEAD + 4*NN)        // NE u32 next-pointers
#define WS_STAGE (WS_PREV + NE)          // NE float4 = {e0, e1, e0*xs, e1*xs}
#define WS_END   (WS_STAGE + 4*NE)
#define WS_NEED_BYTES ((size_t)WS_END * 4 + 256)

#define LEND 0xFFFFFFFFu

static_assert(((WS_STAGE * 4) % 16) == 0, "stage 16B alignment");
static_assert(NE % 4 == 0, "edge unroll");

// ---------------- shared score machinery ----------------
#define STEP(wl_, wr_, we_, bb_, at_, xs_, xd_, ae_, acc_)                 \
  { float tt = fmaf(we_, ae_, bb_); tt = fmaf(wr_, xd_, tt);               \
    tt = fmaf(wl_, xs_, tt); acc_ = fmaf(fabsf(tt), at_, acc_); }

#define STEP4(c, q0, q1, q2, q3)                                           \
  STEP(wl.c, wr.c, we.c, bb.c, at.c, xs0, xd0, ae0, q0)                    \
  STEP(wl.c, wr.c, we.c, bb.c, at.c, xs1, xd1, ae1, q1)                    \
  STEP(wl.c, wr.c, we.c, bb.c, at.c, xs2, xd2, ae2, q2)                    \
  STEP(wl.c, wr.c, we.c, bb.c, at.c, xs3, xd3, ae3, q3)

#define SCORE_CORE                                                         \
  int4 s4 = *(const int4*)&ei[base];                                       \
  int4 dd4 = *(const int4*)&ei[NE + base];                                 \
  float4 ae4 = *(const float4*)&eattr[base];                               \
  float xs0 = x[s4.x], xs1 = x[s4.y], xs2 = x[s4.z], xs3 = x[s4.w];        \
  float xd0 = x[dd4.x], xd1 = x[dd4.y], xd2 = x[dd4.z], xd3 = x[dd4.w];    \
  float ae0 = ae4.x, ae1 = ae4.y, ae2 = ae4.z, ae3 = ae4.w;

#define SCORE_LOOPS                                                        \
  float a00 = 0.f, a01 = 0.f, a02 = 0.f, a03 = 0.f;                        \
  float a10 = 0.f, a11 = 0.f, a12 = 0.f, a13 = 0.f;                        \
  _Pragma("unroll 2")                                                      \
  for (int j = 0; j < 128; j += 4) {                                       \
    float4 wl = *(const float4*)&sWl[j];                                   \
    float4 wr = *(const float4*)&sWr[j];                                   \
    float4 we = *(const float4*)&sWe[j];                                   \
    float4 bb = *(const float4*)&sB[j];                                    \
    float4 at = *(const float4*)&sAt[j];                                   \
    STEP4(x, a00, a01, a02, a03)                                           \
    STEP4(y, a00, a01, a02, a03)                                           \
    STEP4(z, a00, a01, a02, a03)                                           \
    STEP4(w, a00, a01, a02, a03)                                           \
  }                                                                        \
  _Pragma("unroll 2")                                                      \
  for (int j = 128; j < 256; j += 4) {                                     \
    float4 wl = *(const float4*)&sWl[j];                                   \
    float4 wr = *(const float4*)&sWr[j];                                   \
    float4 we = *(const float4*)&sWe[j];                                   \
    float4 bb = *(const float4*)&sB[j];                                    \
    float4 at = *(const float4*)&sAt[j];                                   \
    STEP4(x, a10, a11, a12, a13)                                           \
    STEP4(y, a10, a11, a12, a13)                                           \
    STEP4(z, a10, a11, a12, a13)                                           \
    STEP4(w, a10, a11, a12, a13)                                           \
  }                                                                        \
  float4 c0 = *(const float4*)&ws[WS_C];                                   \
  float4 c1 = *(const float4*)&ws[WS_C + 4];

#define SMEM_WEIGHTS_DECL                                                  \
  __shared__ __align__(16) float sWl[256], sWr[256], sWe[256], sB[256], sAt[256];

#define SMEM_WEIGHTS_LOAD                                                  \
  { int t = threadIdx.x;                                                   \
    sWl[t] = Wl[t]; sWr[t] = Wr[t]; sWe[t] = We[t];                        \
    sB[t] = bl[t] + br[t]; sAt[t] = att[t]; }                              \
  __syncthreads();

#define SCORES(xs_, xd_, ae_, accA, accB, out0, out1)                      \
  { float lin0 = fmaf(c0.x, xs_, fmaf(c0.y, xd_, fmaf(c0.z, ae_, c0.w))); \
    out0 = fmaf(0.4f, accA, 0.6f * lin0);                                  \
    float lin1 = fmaf(c1.x, xs_, fmaf(c1.y, xd_, fmaf(c1.z, ae_, c1.w))); \
    out1 = fmaf(0.4f, accB, 0.6f * lin1); }

// ---------------- k0: init + attention-dot constants ----------------
extern "C" __global__ __launch_bounds__(256)
void k0_init(float* __restrict__ ws,
             const float* __restrict__ att, const float* __restrict__ Wl,
             const float* __restrict__ Wr, const float* __restrict__ We,
             const float* __restrict__ bl, const float* __restrict__ br,
             float* __restrict__ out, int dense)
{
  int tid = blockIdx.x * 256 + threadIdx.x;
  int nt = gridDim.x * 256;
  if (dense) {
    unsigned* head = (unsigned*)(ws + WS_HEAD);
    for (int i = tid; i < 4 * NN; i += nt) head[i] = LEND;
    if (tid < 14) ws[WS_MOM + tid] = 0.f;
  } else {
    for (int i = tid; i < 4 * NN; i += nt) ws[WS_ACC + i] = 0.f;
    for (int i = tid; i < 256; i += nt) ws[WS_BNSUM + i] = 0.f;
  }
  for (int i = tid; i < NG * 128; i += nt) out[i] = 0.f;
  if (blockIdx.x == 0) {
    __shared__ float red[4][256];
    int t = threadIdx.x;                    // t = h*128 + d
    float a = att[t];
    red[0][t] = a * Wl[t];
    red[1][t] = a * Wr[t];
    red[2][t] = a * We[t];
    red[3][t] = a * (bl[t] + br[t]);
    __syncthreads();
    if (t < 8) {
      int k = t >> 1, h = t & 1;
      float s = 0.f;
      for (int d = 0; d < 128; ++d) s += red[k][h * 128 + d];
      ws[WS_C + h * 4 + k] = s;
    }
  }
}

// ---------------- ke: fused score+exp, 4-chain linked-list staging ----------------
extern "C" __global__ __launch_bounds__(256)
void ke_edge(const int* __restrict__ ei, const float* __restrict__ x,
             const float* __restrict__ eattr,
             const float* __restrict__ Wl, const float* __restrict__ Wr,
             const float* __restrict__ We, const float* __restrict__ bl,
             const float* __restrict__ br, const float* __restrict__ att,
             float* __restrict__ ws)
{
  SMEM_WEIGHTS_DECL
  SMEM_WEIGHTS_LOAD
  int base = (blockIdx.x * 256 + threadIdx.x) * 4;
  if (base >= NE) return;
  SCORE_CORE
  unsigned* head = (unsigned*)(ws + WS_HEAD);
  // random exchanges issued early; results consumed only at the very end
  unsigned pv0 = atomicExch(&head[4 * dd4.x + 0], (unsigned)(base + 0));
  unsigned pv1 = atomicExch(&head[4 * dd4.y + 1], (unsigned)(base + 1));
  unsigned pv2 = atomicExch(&head[4 * dd4.z + 2], (unsigned)(base + 2));
  unsigned pv3 = atomicExch(&head[4 * dd4.w + 3], (unsigned)(base + 3));
  SCORE_LOOPS
  float4* stage = (float4*)(ws + WS_STAGE);
  unsigned* prev = (unsigned*)(ws + WS_PREV);
  float s0, s1;
  float4 pay0, pay1, pay2, pay3;
#define PAY(xs_, xd_, ae_, accA, accB, pp)                                 \
  { SCORES(xs_, xd_, ae_, accA, accB, s0, s1)                              \
    float e0 = __expf(s0), e1 = __expf(s1);                                \
    pp = make_float4(e0, e1, e0 * xs_, e1 * xs_); }
  PAY(xs0, xd0, ae0, a00, a10, pay0)
  PAY(xs1, xd1, ae1, a01, a11, pay1)
  PAY(xs2, xd2, ae2, a02, a12, pay2)
  PAY(xs3, xd3, ae3, a03, a13, pay3)
#undef PAY
  stage[base + 0] = pay0;
  stage[base + 1] = pay1;
  stage[base + 2] = pay2;
  stage[base + 3] = pay3;
  *(uint4*)&prev[base] = make_uint4(pv0, pv1, pv2, pv3);
}

// ---------------- kfm: chain-walk gather + 14-moment BN reduction ----------------
// Each thread owns <=1 node, so per-thread f-products are exact moments.
extern "C" __global__ __launch_bounds__(256)
void kfm_gather(float* __restrict__ ws)
{
  int n = blockIdx.x * 256 + threadIdx.x;
  const int t = threadIdx.x;
  float f1 = 0.f, f2 = 0.f, f3 = 0.f, f4 = 0.f;
  if (n < NN) {
    const unsigned* head = (const unsigned*)(ws + WS_HEAD);
    const unsigned* prev = (const unsigned*)(ws + WS_PREV);
    const float4* stage = (const float4*)(ws + WS_STAGE);
    uint4 p = *(const uint4*)&head[4 * n];
    float4 A0 = make_float4(0.f, 0.f, 0.f, 0.f);
    float4 A1 = A0, A2 = A0, A3 = A0;
    while ((p.x & p.y & p.z & p.w) != LEND) {
#define HOP(pc, Ac)                                                        \
      if (pc != LEND) {                                                    \
        float4 q = stage[pc];                                              \
        unsigned np = prev[pc];                                            \
        Ac.x += q.x; Ac.y += q.y; Ac.z += q.z; Ac.w += q.w;                \
        pc = np;                                                           \
      }
      HOP(p.x, A0) HOP(p.y, A1) HOP(p.z, A2) HOP(p.w, A3)
#undef HOP
    }
    float den0 = (A0.x + A1.x) + (A2.x + A3.x);
    float den1 = (A0.y + A1.y) + (A2.y + A3.y);
    float t10  = (A0.z + A1.z) + (A2.z + A3.z);
    float t11  = (A0.w + A1.w) + (A2.w + A3.w);
    *(float4*)&ws[WS_ACC + 4 * n] = make_float4(den0, den1, t10, t11);
    float r0 = 1.f / (den0 + 1e-16f);
    float r1 = 1.f / (den1 + 1e-16f);
    f1 = den0 * r0; f2 = t10 * r0; f3 = den1 * r1; f4 = t11 * r1;
  }
  // moments: S1..S4, M11,M12,M13,M14,M22,M23,M24,M33,M34,M44
  float pm[14] = { f1, f2, f3, f4,
                   f1*f1, f1*f2, f1*f3, f1*f4,
                   f2*f2, f2*f3, f2*f4,
                   f3*f3, f3*f4, f4*f4 };
#pragma unroll
  for (int k = 0; k < 14; ++k) {
    float v = pm[k];
#pragma unroll
    for (int m = 32; m >= 1; m >>= 1) v += __shfl_xor(v, m);
    pm[k] = v;
  }
  __shared__ float smom[56];
  int wid = t >> 6, lane = t & 63;
  if (lane == 0) {
#pragma unroll
    for (int k = 0; k < 14; ++k) smom[wid * 14 + k] = pm[k];
  }
  __syncthreads();
  if (t < 14) {
    float s = smom[t] + smom[14 + t] + smom[28 + t] + smom[42 + t];
    if (s != 0.f) atomicAdd(&ws[WS_MOM + t], s);
  }
}

// ---------------- k4m: BN from moments + leaky_relu + graph pooling ----------------
extern "C" __global__ __launch_bounds__(256)
void k4m_pool(const int* __restrict__ batch,
              const float* __restrict__ Wl, const float* __restrict__ bl,
              const float* __restrict__ bias, const float* __restrict__ gamma,
              const float* __restrict__ beta,
              float* __restrict__ ws, float* __restrict__ out)
{
  const int CHUNK = (NN + (int)gridDim.x - 1) / (int)gridDim.x;
  int n0 = blockIdx.x * CHUNK;
  if (n0 >= NN) return;
  int n1 = n0 + CHUNK; if (n1 > NN) n1 = NN;
  int t = threadIdx.x;
  int d = t & 127;
  int row = t >> 7;
  float S1 = ws[WS_MOM + 0], S2 = ws[WS_MOM + 1];
  float S3 = ws[WS_MOM + 2], S4 = ws[WS_MOM + 3];
  float M11 = ws[WS_MOM + 4], M12 = ws[WS_MOM + 5], M13 = ws[WS_MOM + 6];
  float M14 = ws[WS_MOM + 7], M22 = ws[WS_MOM + 8], M23 = ws[WS_MOM + 9];
  float M24 = ws[WS_MOM + 10], M33 = ws[WS_MOM + 11], M34 = ws[WS_MOM + 12];
  float M44 = ws[WS_MOM + 13];
  float g1 = 0.5f * bl[d], g2 = 0.5f * Wl[d];
  float g3 = 0.5f * bl[128 + d], g4 = 0.5f * Wl[128 + d];
  float g5 = bias[d];
  const float invN = 1.f / (float)NN;
  float dotS = g1 * S1 + g2 * S2 + g3 * S3 + g4 * S4;
  float mean = (dotS + (float)NN * g5) * invN;
  float sumsq = g1*g1*M11 + g2*g2*M22 + g3*g3*M33 + g4*g4*M44
              + 2.f*(g1*g2*M12 + g1*g3*M13 + g1*g4*M14
                   + g2*g3*M23 + g2*g4*M24 + g3*g4*M34)
              + 2.f*g5*dotS + (float)NN*g5*g5;
  float var = fmaf(sumsq, invN, -mean * mean);
  float scale = gamma[d] * rsqrtf(var + 1e-5f);
  float shift = fmaf(-mean, scale, beta[d]);
  __shared__ float pool[4][128];
  for (int i = t; i < 512; i += 256) ((float*)pool)[i] = 0.f;
  __syncthreads();
  int g0 = batch[n0];
  for (int n = n0 + row; n < n1; n += 2) {
    float4 a = *(const float4*)&ws[WS_ACC + 4 * n];
    float r0 = 1.f / (a.x + 1e-16f);
    float r1 = 1.f / (a.y + 1e-16f);
    float o = g1 * (a.x * r0) + g2 * (a.z * r0)
            + g3 * (a.y * r1) + g4 * (a.w * r1) + g5;
    float v = fmaf(o, scale, shift);
    v = v > 0.f ? v : 0.01f * v;
    int g = batch[n];
    int slot = g - g0;                    // >= 0: batch is sorted
    if (slot < 4) atomicAdd(&pool[slot][d], v);
    else atomicAdd(&out[g * 128 + d], v);
  }
  __syncthreads();
  for (int i = t; i < 512; i += 256) {
    int slot = i >> 7, dd = i & 127;
    int g = g0 + slot;
    float v = pool[slot][dd];
    if (g < NG && v != 0.f) atomicAdd(&out[g * 128 + dd], v);
  }
}

// ==================== fallback path (small ws): direct atomics + BNSUM ====================
extern "C" __global__ __launch_bounds__(256)
void k12f(const int* __restrict__ ei, const float* __restrict__ x,
          const float* __restrict__ eattr,
          const float* __restrict__ Wl, const float* __restrict__ Wr,
          const float* __restrict__ We, const float* __restrict__ bl,
          const float* __restrict__ br, const float* __restrict__ att,
          float* __restrict__ ws)
{
  SMEM_WEIGHTS_DECL
  SMEM_WEIGHTS_LOAD
  int base = (blockIdx.x * 256 + threadIdx.x) * 4;
  if (base >= NE) return;
  SCORE_CORE
  SCORE_LOOPS
  float* acc = ws + WS_ACC;
  float s0, s1;
#define EPI2(xs_, xd_, ae_, accA, accB, dsti)                              \
  { SCORES(xs_, xd_, ae_, accA, accB, s0, s1)                              \
    float e0 = __expf(s0), e1 = __expf(s1);                                \
    float* a = &acc[4 * dsti];                                             \
    atomicAdd(a + 0, e0); atomicAdd(a + 1, e1);                            \
    atomicAdd(a + 2, e0 * xs_); atomicAdd(a + 3, e1 * xs_); }
  EPI2(xs0, xd0, ae0, a00, a10, dd4.x)
  EPI2(xs1, xd1, ae1, a01, a11, dd4.y)
  EPI2(xs2, xd2, ae2, a02, a12, dd4.z)
  EPI2(xs3, xd3, ae3, a03, a13, dd4.w)
#undef EPI2
}

__device__ __forceinline__ float node_out4(float4 a, float wl0, float wl1,
                                           float b0, float b1, float bs)
{
  float r0 = 1.f / (a.x + 1e-16f);
  float r1 = 1.f / (a.y + 1e-16f);
  return 0.5f * (fmaf(wl0, a.z * r0, b0 * (a.x * r0)) +
                 fmaf(wl1, a.w * r1, b1 * (a.y * r1))) + bs;
}

extern "C" __global__ __launch_bounds__(256)
void k3_stats(const float* __restrict__ Wl, const float* __restrict__ bl,
              const float* __restrict__ bias, float* __restrict__ ws)
{
  int d = threadIdx.x & 127;
  int row = threadIdx.x >> 7;
  float wl0 = Wl[d], wl1 = Wl[128 + d];
  float b0 = bl[d], b1 = bl[128 + d];
  float bs = bias[d];
  float sum = 0.f, sq = 0.f;
  for (int n = blockIdx.x * 2 + row; n < NN; n += gridDim.x * 2) {
    float4 a = *(const float4*)&ws[WS_ACC + 4 * n];
    float o = node_out4(a, wl0, wl1, b0, b1, bs);
    sum += o;
    sq = fmaf(o, o, sq);
  }
  __shared__ float l1[256], l2[256];
  l1[threadIdx.x] = sum; l2[threadIdx.x] = sq;
  __syncthreads();
  if (row == 0) {
    atomicAdd(&ws[WS_BNSUM + d], l1[d] + l1[128 + d]);
    atomicAdd(&ws[WS_BNSQ + d], l2[d] + l2[128 + d]);
  }
}

extern "C" __global__ __launch_bounds__(256)
void k4_pool(const int* __restrict__ batch,
             const float* __restrict__ Wl, const float* __restrict__ bl,
             const float* __restrict__ bias, const float* __restrict__ gamma,
             const float* __restrict__ beta,
             float* __restrict__ ws, float* __restrict__ out)
{
  const int CHUNK = (NN + (int)gridDim.x - 1) / (int)gridDim.x;
  int n0 = blockIdx.x * CHUNK;
  if (n0 >= NN) return;
  int n1 = n0 + CHUNK; if (n1 > NN) n1 = NN;
  int d = threadIdx.x & 127;
  int row = threadIdx.x >> 7;
  const float invN = 1.f / (float)NN;
  float mean = ws[WS_BNSUM + d] * invN;
  float var = fmaf(ws[WS_BNSQ + d], invN, -mean * mean);
  float scale = gamma[d] * rsqrtf(var + 1e-5f);
  float shift = fmaf(-mean, scale, beta[d]);
  float wl0 = Wl[d], wl1 = Wl[128 + d];
  float b0 = bl[d], b1 = bl[128 + d];
  float bs = bias[d];
  __shared__ float pool[4][128];
  for (int i = threadIdx.x; i < 512; i += 256) ((float*)pool)[i] = 0.f;
  __syncthreads();
  int g0 = batch[n0];
  for (int n = n0 + row; n < n1; n += 2) {
    float4 a = *(const float4*)&ws[WS_ACC + 4 * n];
    float o = node_out4(a, wl0, wl1, b0, b1, bs);
    float v = fmaf(o, scale, shift);
    v = v > 0.f ? v : 0.01f * v;
    int g = batch[n];
    int slot = g - g0;
    if (slot < 4) atomicAdd(&pool[slot][d], v);
    else atomicAdd(&out[g * 128 + d], v);
  }
  __syncthreads();
  for (int i = threadIdx.x; i < 512; i += 256) {
    int slot = i >> 7, dd = i & 127;
    int g = g0 + slot;
    float v = pool[slot][dd];
    if (g < NG && v != 0.f) atomicAdd(&out[g * 128 + dd], v);
  }
}

extern "C" void kernel_launch(void* const* d_in, const int* in_sizes, int n_in,
                              void* d_out, int out_size, void* d_ws, size_t ws_size,
                              hipStream_t stream) {
  const float* x     = (const float*)d_in[0];
  const int*   ei    = (const int*)d_in[1];
  const float* eattr = (const float*)d_in[2];
  const int*   batch = (const int*)d_in[3];
  const float* Wl    = (const float*)d_in[4];
  const float* bl    = (const float*)d_in[5];
  const float* Wr    = (const float*)d_in[6];
  const float* br    = (const float*)d_in[7];
  const float* We    = (const float*)d_in[8];
  const float* att   = (const float*)d_in[9];
  const float* bias  = (const float*)d_in[10];
  const float* gam   = (const float*)d_in[11];
  const float* bet   = (const float*)d_in[12];
  float* ws  = (float*)d_ws;
  float* out = (float*)d_out;

  const bool dense = (ws_size >= WS_NEED_BYTES);
  const int EB = (NE / 4 + 255) / 256;

  hipLaunchKernelGGL(k0_init, dim3(128), dim3(256), 0, stream,
                     ws, att, Wl, Wr, We, bl, br, out, dense ? 1 : 0);
  if (dense) {
    hipLaunchKernelGGL(ke_edge, dim3(EB), dim3(256), 0, stream,
                       ei, x, eattr, Wl, Wr, We, bl, br, att, ws);
    hipLaunchKernelGGL(kfm_gather, dim3((NN + 255) / 256), dim3(256), 0, stream, ws);
    hipLaunchKernelGGL(k4m_pool, dim3(256), dim3(256), 0, stream,
                       batch, Wl, bl, bias, gam, bet, ws, out);
  } else {
    hipLaunchKernelGGL(k12f, dim3(EB), dim3(256), 0, stream,
                       ei, x, eattr, Wl, Wr, We, bl, br, att, ws);
    hipLaunchKernelGGL(k3_stats, dim3(256), dim3(256), 0, stream,
                       Wl, bl, bias, ws);
    hipLaunchKernelGGL(k4_pool, dim3(256), dim3(256), 0, stream,
                       batch, Wl, bl, bias, gam, bet, ws, out);
  }
}

// Round 9
// 191.825 us; speedup vs baseline: 2.9966x; 1.9456x over previous
//
#include <hip/hip_runtime.h>
#include <math.h>

#define NN 50000
#define NE 800000
#define NG 64

// ---------------- ws layout (float offsets) ----------------
#define WS_C     0                       // 8 floats: [h*4 + {att.Wl, att.Wr, att.We, att.B}]
#define WS_ACC   16                      // 4*NN floats: {den0,den1,t10,t11} per node (float4)
#define WS_BNSUM (WS_ACC + 4*NN)         // 128 (fallback path)
#define WS_BNSQ  (WS_BNSUM + 128)        // 128 (fallback path)
#define WS_MOM   WS_BNSUM                // dense path: 14 floats (overlaps BNSUM, paths exclusive)
#define WS_HEAD  (WS_BNSQ + 128)         // 4*NN u32 chain heads (0xFFFFFFFF = end)
#define WS_PREV  (WS_HEAD + 4*NN)        // NE u32 next-pointers
#define WS_STAGE (WS_PREV + NE)          // NE float4 = {e0, e1, e0*xs, e1*xs}
#define WS_END   (WS_STAGE + 4*NE)
#define WS_NEED_BYTES ((size_t)WS_END * 4 + 256)

#define LEND 0xFFFFFFFFu

static_assert(((WS_STAGE * 4) % 16) == 0, "stage 16B alignment");
static_assert(NE % 4 == 0, "edge unroll");

// ---------------- shared score machinery ----------------
#define STEP(wl_, wr_, we_, bb_, at_, xs_, xd_, ae_, acc_)                 \
  { float tt = fmaf(we_, ae_, bb_); tt = fmaf(wr_, xd_, tt);               \
    tt = fmaf(wl_, xs_, tt); acc_ = fmaf(fabsf(tt), at_, acc_); }

#define STEP4(c, q0, q1, q2, q3)                                           \
  STEP(wl.c, wr.c, we.c, bb.c, at.c, xs0, xd0, ae0, q0)                    \
  STEP(wl.c, wr.c, we.c, bb.c, at.c, xs1, xd1, ae1, q1)                    \
  STEP(wl.c, wr.c, we.c, bb.c, at.c, xs2, xd2, ae2, q2)                    \
  STEP(wl.c, wr.c, we.c, bb.c, at.c, xs3, xd3, ae3, q3)

#define SCORE_CORE                                                         \
  int4 s4 = *(const int4*)&ei[base];                                       \
  int4 dd4 = *(const int4*)&ei[NE + base];                                 \
  float4 ae4 = *(const float4*)&eattr[base];                               \
  float xs0 = x[s4.x], xs1 = x[s4.y], xs2 = x[s4.z], xs3 = x[s4.w];        \
  float xd0 = x[dd4.x], xd1 = x[dd4.y], xd2 = x[dd4.z], xd3 = x[dd4.w];    \
  float ae0 = ae4.x, ae1 = ae4.y, ae2 = ae4.z, ae3 = ae4.w;

#define SCORE_LOOPS                                                        \
  float a00 = 0.f, a01 = 0.f, a02 = 0.f, a03 = 0.f;                        \
  float a10 = 0.f, a11 = 0.f, a12 = 0.f, a13 = 0.f;                        \
  _Pragma("unroll 2")                                                      \
  for (int j = 0; j < 128; j += 4) {                                       \
    float4 wl = *(const float4*)&sWl[j];                                   \
    float4 wr = *(const float4*)&sWr[j];                                   \
    float4 we = *(const float4*)&sWe[j];                                   \
    float4 bb = *(const float4*)&sB[j];                                    \
    float4 at = *(const float4*)&sAt[j];                                   \
    STEP4(x, a00, a01, a02, a03)                                           \
    STEP4(y, a00, a01, a02, a03)                                           \
    STEP4(z, a00, a01, a02, a03)                                           \
    STEP4(w, a00, a01, a02, a03)                                           \
  }                                                                        \
  _Pragma("unroll 2")                                                      \
  for (int j = 128; j < 256; j += 4) {                                     \
    float4 wl = *(const float4*)&sWl[j];                                   \
    float4 wr = *(const float4*)&sWr[j];                                   \
    float4 we = *(const float4*)&sWe[j];                                   \
    float4 bb = *(const float4*)&sB[j];                                    \
    float4 at = *(const float4*)&sAt[j];                                   \
    STEP4(x, a10, a11, a12, a13)                                           \
    STEP4(y, a10, a11, a12, a13)                                           \
    STEP4(z, a10, a11, a12, a13)                                           \
    STEP4(w, a10, a11, a12, a13)                                           \
  }                                                                        \
  float4 c0 = *(const float4*)&ws[WS_C];                                   \
  float4 c1 = *(const float4*)&ws[WS_C + 4];

#define SMEM_WEIGHTS_DECL                                                  \
  __shared__ __align__(16) float sWl[256], sWr[256], sWe[256], sB[256], sAt[256];

#define SMEM_WEIGHTS_LOAD                                                  \
  { int t = threadIdx.x;                                                   \
    sWl[t] = Wl[t]; sWr[t] = Wr[t]; sWe[t] = We[t];                        \
    sB[t] = bl[t] + br[t]; sAt[t] = att[t]; }                              \
  __syncthreads();

#define SCORES(xs_, xd_, ae_, accA, accB, out0, out1)                      \
  { float lin0 = fmaf(c0.x, xs_, fmaf(c0.y, xd_, fmaf(c0.z, ae_, c0.w))); \
    out0 = fmaf(0.4f, accA, 0.6f * lin0);                                  \
    float lin1 = fmaf(c1.x, xs_, fmaf(c1.y, xd_, fmaf(c1.z, ae_, c1.w))); \
    out1 = fmaf(0.4f, accB, 0.6f * lin1); }

// ---------------- k0: init + attention-dot constants ----------------
extern "C" __global__ __launch_bounds__(256)
void k0_init(float* __restrict__ ws,
             const float* __restrict__ att, const float* __restrict__ Wl,
             const float* __restrict__ Wr, const float* __restrict__ We,
             const float* __restrict__ bl, const float* __restrict__ br,
             float* __restrict__ out, int dense)
{
  int tid = blockIdx.x * 256 + threadIdx.x;
  int nt = gridDim.x * 256;
  if (dense) {
    unsigned* head = (unsigned*)(ws + WS_HEAD);
    for (int i = tid; i < 4 * NN; i += nt) head[i] = LEND;
    if (tid < 14) ws[WS_MOM + tid] = 0.f;
  } else {
    for (int i = tid; i < 4 * NN; i += nt) ws[WS_ACC + i] = 0.f;
    for (int i = tid; i < 256; i += nt) ws[WS_BNSUM + i] = 0.f;
  }
  for (int i = tid; i < NG * 128; i += nt) out[i] = 0.f;
  if (blockIdx.x == 0) {
    __shared__ float red[4][256];
    int t = threadIdx.x;                    // t = h*128 + d
    float a = att[t];
    red[0][t] = a * Wl[t];
    red[1][t] = a * Wr[t];
    red[2][t] = a * We[t];
    red[3][t] = a * (bl[t] + br[t]);
    __syncthreads();
    if (t < 8) {
      int k = t >> 1, h = t & 1;
      float s = 0.f;
      for (int d = 0; d < 128; ++d) s += red[k][h * 128 + d];
      ws[WS_C + h * 4 + k] = s;
    }
  }
}

// ---------------- ke: fused score+exp, 4-chain linked-list staging ----------------
extern "C" __global__ __launch_bounds__(256)
void ke_edge(const int* __restrict__ ei, const float* __restrict__ x,
             const float* __restrict__ eattr,
             const float* __restrict__ Wl, const float* __restrict__ Wr,
             const float* __restrict__ We, const float* __restrict__ bl,
             const float* __restrict__ br, const float* __restrict__ att,
             float* __restrict__ ws)
{
  SMEM_WEIGHTS_DECL
  SMEM_WEIGHTS_LOAD
  int base = (blockIdx.x * 256 + threadIdx.x) * 4;
  if (base >= NE) return;
  SCORE_CORE
  unsigned* head = (unsigned*)(ws + WS_HEAD);
  // random exchanges issued early; results consumed only at the very end
  unsigned pv0 = atomicExch(&head[4 * dd4.x + 0], (unsigned)(base + 0));
  unsigned pv1 = atomicExch(&head[4 * dd4.y + 1], (unsigned)(base + 1));
  unsigned pv2 = atomicExch(&head[4 * dd4.z + 2], (unsigned)(base + 2));
  unsigned pv3 = atomicExch(&head[4 * dd4.w + 3], (unsigned)(base + 3));
  SCORE_LOOPS
  float4* stage = (float4*)(ws + WS_STAGE);
  unsigned* prev = (unsigned*)(ws + WS_PREV);
  float s0, s1;
  float4 pay0, pay1, pay2, pay3;
#define PAY(xs_, xd_, ae_, accA, accB, pp)                                 \
  { SCORES(xs_, xd_, ae_, accA, accB, s0, s1)                              \
    float e0 = __expf(s0), e1 = __expf(s1);                                \
    pp = make_float4(e0, e1, e0 * xs_, e1 * xs_); }
  PAY(xs0, xd0, ae0, a00, a10, pay0)
  PAY(xs1, xd1, ae1, a01, a11, pay1)
  PAY(xs2, xd2, ae2, a02, a12, pay2)
  PAY(xs3, xd3, ae3, a03, a13, pay3)
#undef PAY
  stage[base + 0] = pay0;
  stage[base + 1] = pay1;
  stage[base + 2] = pay2;
  stage[base + 3] = pay3;
  *(uint4*)&prev[base] = make_uint4(pv0, pv1, pv2, pv3);
}

// ---------------- kfm: chain-walk gather + 14-moment BN reduction ----------------
// 2 threads per node (2 chains each) for 2x latency hiding; lane-pair shuffle
// combines the halves. Each NODE's f-products computed once (even lane), so
// moments stay exact.
extern "C" __global__ __launch_bounds__(256)
void kfm_gather(float* __restrict__ ws)
{
  const int t = threadIdx.x;
  int gid = blockIdx.x * 256 + t;          // 2 threads per node
  int n = gid >> 1;
  int half = gid & 1;
  float f1 = 0.f, f2 = 0.f, f3 = 0.f, f4 = 0.f;
  if (n < NN) {
    const unsigned* head = (const unsigned*)(ws + WS_HEAD);
    const unsigned* prev = (const unsigned*)(ws + WS_PREV);
    const float4* stage = (const float4*)(ws + WS_STAGE);
    uint2 p = *(const uint2*)&head[4 * n + 2 * half];
    float4 A0 = make_float4(0.f, 0.f, 0.f, 0.f);
    float4 A1 = A0;
    while ((p.x & p.y) != LEND) {
#define HOP(pc, Ac)                                                        \
      if (pc != LEND) {                                                    \
        float4 q = stage[pc];                                              \
        unsigned np = prev[pc];                                            \
        Ac.x += q.x; Ac.y += q.y; Ac.z += q.z; Ac.w += q.w;                \
        pc = np;                                                           \
      }
      HOP(p.x, A0) HOP(p.y, A1)
#undef HOP
    }
    float den0 = A0.x + A1.x;
    float den1 = A0.y + A1.y;
    float t10  = A0.z + A1.z;
    float t11  = A0.w + A1.w;
    // combine the two halves of this node (lane pair within the same wave)
    den0 += __shfl_xor(den0, 1);
    den1 += __shfl_xor(den1, 1);
    t10  += __shfl_xor(t10, 1);
    t11  += __shfl_xor(t11, 1);
    if (half == 0) {
      *(float4*)&ws[WS_ACC + 4 * n] = make_float4(den0, den1, t10, t11);
      float r0 = 1.f / (den0 + 1e-16f);
      float r1 = 1.f / (den1 + 1e-16f);
      f1 = den0 * r0; f2 = t10 * r0; f3 = den1 * r1; f4 = t11 * r1;
    }
  }
  // moments: S1..S4, M11,M12,M13,M14,M22,M23,M24,M33,M34,M44
  // (odd lanes contribute zeros — each node counted exactly once)
  float pm[14] = { f1, f2, f3, f4,
                   f1*f1, f1*f2, f1*f3, f1*f4,
                   f2*f2, f2*f3, f2*f4,
                   f3*f3, f3*f4, f4*f4 };
#pragma unroll
  for (int k = 0; k < 14; ++k) {
    float v = pm[k];
#pragma unroll
    for (int m = 32; m >= 1; m >>= 1) v += __shfl_xor(v, m);
    pm[k] = v;
  }
  __shared__ float smom[56];
  int wid = t >> 6, lane = t & 63;
  if (lane == 0) {
#pragma unroll
    for (int k = 0; k < 14; ++k) smom[wid * 14 + k] = pm[k];
  }
  __syncthreads();
  if (t < 14) {
    float s = smom[t] + smom[14 + t] + smom[28 + t] + smom[42 + t];
    if (s != 0.f) atomicAdd(&ws[WS_MOM + t], s);
  }
}

// ---------------- k4m: BN from moments + leaky_relu + graph pooling ----------------
extern "C" __global__ __launch_bounds__(256)
void k4m_pool(const int* __restrict__ batch,
              const float* __restrict__ Wl, const float* __restrict__ bl,
              const float* __restrict__ bias, const float* __restrict__ gamma,
              const float* __restrict__ beta,
              float* __restrict__ ws, float* __restrict__ out)
{
  const int CHUNK = (NN + (int)gridDim.x - 1) / (int)gridDim.x;
  int n0 = blockIdx.x * CHUNK;
  if (n0 >= NN) return;
  int n1 = n0 + CHUNK; if (n1 > NN) n1 = NN;
  int t = threadIdx.x;
  int d = t & 127;
  int row = t >> 7;
  float S1 = ws[WS_MOM + 0], S2 = ws[WS_MOM + 1];
  float S3 = ws[WS_MOM + 2], S4 = ws[WS_MOM + 3];
  float M11 = ws[WS_MOM + 4], M12 = ws[WS_MOM + 5], M13 = ws[WS_MOM + 6];
  float M14 = ws[WS_MOM + 7], M22 = ws[WS_MOM + 8], M23 = ws[WS_MOM + 9];
  float M24 = ws[WS_MOM + 10], M33 = ws[WS_MOM + 11], M34 = ws[WS_MOM + 12];
  float M44 = ws[WS_MOM + 13];
  float g1 = 0.5f * bl[d], g2 = 0.5f * Wl[d];
  float g3 = 0.5f * bl[128 + d], g4 = 0.5f * Wl[128 + d];
  float g5 = bias[d];
  const float invN = 1.f / (float)NN;
  float dotS = g1 * S1 + g2 * S2 + g3 * S3 + g4 * S4;
  float mean = (dotS + (float)NN * g5) * invN;
  float sumsq = g1*g1*M11 + g2*g2*M22 + g3*g3*M33 + g4*g4*M44
              + 2.f*(g1*g2*M12 + g1*g3*M13 + g1*g4*M14
                   + g2*g3*M23 + g2*g4*M24 + g3*g4*M34)
              + 2.f*g5*dotS + (float)NN*g5*g5;
  float var = fmaf(sumsq, invN, -mean * mean);
  float scale = gamma[d] * rsqrtf(var + 1e-5f);
  float shift = fmaf(-mean, scale, beta[d]);
  __shared__ float pool[4][128];
  for (int i = t; i < 512; i += 256) ((float*)pool)[i] = 0.f;
  __syncthreads();
  int g0 = batch[n0];
  for (int n = n0 + row; n < n1; n += 2) {
    float4 a = *(const float4*)&ws[WS_ACC + 4 * n];
    float r0 = 1.f / (a.x + 1e-16f);
    float r1 = 1.f / (a.y + 1e-16f);
    float o = g1 * (a.x * r0) + g2 * (a.z * r0)
            + g3 * (a.y * r1) + g4 * (a.w * r1) + g5;
    float v = fmaf(o, scale, shift);
    v = v > 0.f ? v : 0.01f * v;
    int g = batch[n];
    int slot = g - g0;                    // >= 0: batch is sorted
    if (slot < 4) atomicAdd(&pool[slot][d], v);
    else atomicAdd(&out[g * 128 + d], v);
  }
  __syncthreads();
  for (int i = t; i < 512; i += 256) {
    int slot = i >> 7, dd = i & 127;
    int g = g0 + slot;
    float v = pool[slot][dd];
    if (g < NG && v != 0.f) atomicAdd(&out[g * 128 + dd], v);
  }
}

// ==================== fallback path (small ws): direct atomics + BNSUM ====================
extern "C" __global__ __launch_bounds__(256)
void k12f(const int* __restrict__ ei, const float* __restrict__ x,
          const float* __restrict__ eattr,
          const float* __restrict__ Wl, const float* __restrict__ Wr,
          const float* __restrict__ We, const float* __restrict__ bl,
          const float* __restrict__ br, const float* __restrict__ att,
          float* __restrict__ ws)
{
  SMEM_WEIGHTS_DECL
  SMEM_WEIGHTS_LOAD
  int base = (blockIdx.x * 256 + threadIdx.x) * 4;
  if (base >= NE) return;
  SCORE_CORE
  SCORE_LOOPS
  float* acc = ws + WS_ACC;
  float s0, s1;
#define EPI2(xs_, xd_, ae_, accA, accB, dsti)                              \
  { SCORES(xs_, xd_, ae_, accA, accB, s0, s1)                              \
    float e0 = __expf(s0), e1 = __expf(s1);                                \
    float* a = &acc[4 * dsti];                                             \
    atomicAdd(a + 0, e0); atomicAdd(a + 1, e1);                            \
    atomicAdd(a + 2, e0 * xs_); atomicAdd(a + 3, e1 * xs_); }
  EPI2(xs0, xd0, ae0, a00, a10, dd4.x)
  EPI2(xs1, xd1, ae1, a01, a11, dd4.y)
  EPI2(xs2, xd2, ae2, a02, a12, dd4.z)
  EPI2(xs3, xd3, ae3, a03, a13, dd4.w)
#undef EPI2
}

__device__ __forceinline__ float node_out4(float4 a, float wl0, float wl1,
                                           float b0, float b1, float bs)
{
  float r0 = 1.f / (a.x + 1e-16f);
  float r1 = 1.f / (a.y + 1e-16f);
  return 0.5f * (fmaf(wl0, a.z * r0, b0 * (a.x * r0)) +
                 fmaf(wl1, a.w * r1, b1 * (a.y * r1))) + bs;
}

extern "C" __global__ __launch_bounds__(256)
void k3_stats(const float* __restrict__ Wl, const float* __restrict__ bl,
              const float* __restrict__ bias, float* __restrict__ ws)
{
  int d = threadIdx.x & 127;
  int row = threadIdx.x >> 7;
  float wl0 = Wl[d], wl1 = Wl[128 + d];
  float b0 = bl[d], b1 = bl[128 + d];
  float bs = bias[d];
  float sum = 0.f, sq = 0.f;
  for (int n = blockIdx.x * 2 + row; n < NN; n += gridDim.x * 2) {
    float4 a = *(const float4*)&ws[WS_ACC + 4 * n];
    float o = node_out4(a, wl0, wl1, b0, b1, bs);
    sum += o;
    sq = fmaf(o, o, sq);
  }
  __shared__ float l1[256], l2[256];
  l1[threadIdx.x] = sum; l2[threadIdx.x] = sq;
  __syncthreads();
  if (row == 0) {
    atomicAdd(&ws[WS_BNSUM + d], l1[d] + l1[128 + d]);
    atomicAdd(&ws[WS_BNSQ + d], l2[d] + l2[128 + d]);
  }
}

extern "C" __global__ __launch_bounds__(256)
void k4_pool(const int* __restrict__ batch,
             const float* __restrict__ Wl, const float* __restrict__ bl,
             const float* __restrict__ bias, const float* __restrict__ gamma,
             const float* __restrict__ beta,
             float* __restrict__ ws, float* __restrict__ out)
{
  const int CHUNK = (NN + (int)gridDim.x - 1) / (int)gridDim.x;
  int n0 = blockIdx.x * CHUNK;
  if (n0 >= NN) return;
  int n1 = n0 + CHUNK; if (n1 > NN) n1 = NN;
  int d = threadIdx.x & 127;
  int row = threadIdx.x >> 7;
  const float invN = 1.f / (float)NN;
  float mean = ws[WS_BNSUM + d] * invN;
  float var = fmaf(ws[WS_BNSQ + d], invN, -mean * mean);
  float scale = gamma[d] * rsqrtf(var + 1e-5f);
  float shift = fmaf(-mean, scale, beta[d]);
  float wl0 = Wl[d], wl1 = Wl[128 + d];
  float b0 = bl[d], b1 = bl[128 + d];
  float bs = bias[d];
  __shared__ float pool[4][128];
  for (int i = threadIdx.x; i < 512; i += 256) ((float*)pool)[i] = 0.f;
  __syncthreads();
  int g0 = batch[n0];
  for (int n = n0 + row; n < n1; n += 2) {
    float4 a = *(const float4*)&ws[WS_ACC + 4 * n];
    float o = node_out4(a, wl0, wl1, b0, b1, bs);
    float v = fmaf(o, scale, shift);
    v = v > 0.f ? v : 0.01f * v;
    int g = batch[n];
    int slot = g - g0;
    if (slot < 4) atomicAdd(&pool[slot][d], v);
    else atomicAdd(&out[g * 128 + d], v);
  }
  __syncthreads();
  for (int i = threadIdx.x; i < 512; i += 256) {
    int slot = i >> 7, dd = i & 127;
    int g = g0 + slot;
    float v = pool[slot][dd];
    if (g < NG && v != 0.f) atomicAdd(&out[g * 128 + dd], v);
  }
}

extern "C" void kernel_launch(void* const* d_in, const int* in_sizes, int n_in,
                              void* d_out, int out_size, void* d_ws, size_t ws_size,
                              hipStream_t stream) {
  const float* x     = (const float*)d_in[0];
  const int*   ei    = (const int*)d_in[1];
  const float* eattr = (const float*)d_in[2];
  const int*   batch = (const int*)d_in[3];
  const float* Wl    = (const float*)d_in[4];
  const float* bl    = (const float*)d_in[5];
  const float* Wr    = (const float*)d_in[6];
  const float* br    = (const float*)d_in[7];
  const float* We    = (const float*)d_in[8];
  const float* att   = (const float*)d_in[9];
  const float* bias  = (const float*)d_in[10];
  const float* gam   = (const float*)d_in[11];
  const float* bet   = (const float*)d_in[12];
  float* ws  = (float*)d_ws;
  float* out = (float*)d_out;

  const bool dense = (ws_size >= WS_NEED_BYTES);
  const int EB = (NE / 4 + 255) / 256;

  hipLaunchKernelGGL(k0_init, dim3(128), dim3(256), 0, stream,
                     ws, att, Wl, Wr, We, bl, br, out, dense ? 1 : 0);
  if (dense) {
    hipLaunchKernelGGL(ke_edge, dim3(EB), dim3(256), 0, stream,
                       ei, x, eattr, Wl, Wr, We, bl, br, att, ws);
    hipLaunchKernelGGL(kfm_gather, dim3((2 * NN + 255) / 256), dim3(256), 0, stream, ws);
    hipLaunchKernelGGL(k4m_pool, dim3(256), dim3(256), 0, stream,
                       batch, Wl, bl, bias, gam, bet, ws, out);
  } else {
    hipLaunchKernelGGL(k12f, dim3(EB), dim3(256), 0, stream,
                       ei, x, eattr, Wl, Wr, We, bl, br, att, ws);
    hipLaunchKernelGGL(k3_stats, dim3(256), dim3(256), 0, stream,
                       Wl, bl, bias, ws);
    hipLaunchKernelGGL(k4_pool, dim3(256), dim3(256), 0, stream,
                       batch, Wl, bl, bias, gam, bet, ws, out);
  }
}

// Round 10
// 186.427 us; speedup vs baseline: 3.0834x; 1.0290x over previous
//
#include <hip/hip_runtime.h>
#include <math.h>

#define NN 50000
#define NE 800000
#define NG 64

// ---------------- ws layout (float offsets) ----------------
#define WS_C     0                       // 8 floats: [h*4 + {att.Wl, att.Wr, att.We, att.B}]
#define WS_ACC   16                      // 4*NN floats: {den0,den1,t10,t11} per node (float4)
#define WS_BNSUM (WS_ACC + 4*NN)         // 128 (fallback path)
#define WS_BNSQ  (WS_BNSUM + 128)        // 128 (fallback path)
#define WS_MOM   WS_BNSUM                // dense path: 14 floats (overlaps BNSUM, paths exclusive)
#define WS_HEAD  (WS_BNSQ + 128)         // 4*NN u32 chain heads (0xFFFFFFFF = end)
#define WS_PREV  (WS_HEAD + 4*NN)        // NE u32 next-pointers
#define WS_STAGE (WS_PREV + NE)          // NE float4 = {e0, e1, e0*xs, e1*xs}
#define WS_END   (WS_STAGE + 4*NE)
#define WS_NEED_BYTES ((size_t)WS_END * 4 + 256)

#define LEND 0xFFFFFFFFu

static_assert(((WS_STAGE * 4) % 16) == 0, "stage 16B alignment");
static_assert(NE % 4 == 0, "edge unroll");

// ---------------- shared score machinery ----------------
#define STEP(wl_, wr_, we_, bb_, at_, xs_, xd_, ae_, acc_)                 \
  { float tt = fmaf(we_, ae_, bb_); tt = fmaf(wr_, xd_, tt);               \
    tt = fmaf(wl_, xs_, tt); acc_ = fmaf(fabsf(tt), at_, acc_); }

#define SMEM_WEIGHTS_DECL                                                  \
  __shared__ __align__(16) float sWl[256], sWr[256], sWe[256], sB[256], sAt[256];

#define SMEM_WEIGHTS_LOAD                                                  \
  { int t_ = threadIdx.x;                                                  \
    sWl[t_] = Wl[t_]; sWr[t_] = Wr[t_]; sWe[t_] = We[t_];                  \
    sB[t_] = bl[t_] + br[t_]; sAt[t_] = att[t_]; }                         \
  __syncthreads();

#define SCORES(xs_, xd_, ae_, accA, accB, out0, out1)                      \
  { float lin0 = fmaf(c0.x, xs_, fmaf(c0.y, xd_, fmaf(c0.z, ae_, c0.w))); \
    out0 = fmaf(0.4f, accA, 0.6f * lin0);                                  \
    float lin1 = fmaf(c1.x, xs_, fmaf(c1.y, xd_, fmaf(c1.z, ae_, c1.w))); \
    out1 = fmaf(0.4f, accB, 0.6f * lin1); }

// ---- 4-edge variants (fallback path) ----
#define STEP4(c, q0, q1, q2, q3)                                           \
  STEP(wl.c, wr.c, we.c, bb.c, at.c, xs0, xd0, ae0, q0)                    \
  STEP(wl.c, wr.c, we.c, bb.c, at.c, xs1, xd1, ae1, q1)                    \
  STEP(wl.c, wr.c, we.c, bb.c, at.c, xs2, xd2, ae2, q2)                    \
  STEP(wl.c, wr.c, we.c, bb.c, at.c, xs3, xd3, ae3, q3)

#define SCORE_CORE                                                         \
  int4 s4 = *(const int4*)&ei[base];                                       \
  int4 dd4 = *(const int4*)&ei[NE + base];                                 \
  float4 ae4 = *(const float4*)&eattr[base];                               \
  float xs0 = x[s4.x], xs1 = x[s4.y], xs2 = x[s4.z], xs3 = x[s4.w];        \
  float xd0 = x[dd4.x], xd1 = x[dd4.y], xd2 = x[dd4.z], xd3 = x[dd4.w];    \
  float ae0 = ae4.x, ae1 = ae4.y, ae2 = ae4.z, ae3 = ae4.w;

#define SCORE_LOOPS                                                        \
  float a00 = 0.f, a01 = 0.f, a02 = 0.f, a03 = 0.f;                        \
  float a10 = 0.f, a11 = 0.f, a12 = 0.f, a13 = 0.f;                        \
  _Pragma("unroll 2")                                                      \
  for (int j = 0; j < 128; j += 4) {                                       \
    float4 wl = *(const float4*)&sWl[j];                                   \
    float4 wr = *(const float4*)&sWr[j];                                   \
    float4 we = *(const float4*)&sWe[j];                                   \
    float4 bb = *(const float4*)&sB[j];                                    \
    float4 at = *(const float4*)&sAt[j];                                   \
    STEP4(x, a00, a01, a02, a03)                                           \
    STEP4(y, a00, a01, a02, a03)                                           \
    STEP4(z, a00, a01, a02, a03)                                           \
    STEP4(w, a00, a01, a02, a03)                                           \
  }                                                                        \
  _Pragma("unroll 2")                                                      \
  for (int j = 128; j < 256; j += 4) {                                     \
    float4 wl = *(const float4*)&sWl[j];                                   \
    float4 wr = *(const float4*)&sWr[j];                                   \
    float4 we = *(const float4*)&sWe[j];                                   \
    float4 bb = *(const float4*)&sB[j];                                    \
    float4 at = *(const float4*)&sAt[j];                                   \
    STEP4(x, a10, a11, a12, a13)                                           \
    STEP4(y, a10, a11, a12, a13)                                           \
    STEP4(z, a10, a11, a12, a13)                                           \
    STEP4(w, a10, a11, a12, a13)                                           \
  }                                                                        \
  float4 c0 = *(const float4*)&ws[WS_C];                                   \
  float4 c1 = *(const float4*)&ws[WS_C + 4];

// ---- 2-edge variants (dense ke path: more waves -> more outstanding exch) ----
#define STEP2(c, q0, q1)                                                   \
  STEP(wl.c, wr.c, we.c, bb.c, at.c, xs0, xd0, ae0, q0)                    \
  STEP(wl.c, wr.c, we.c, bb.c, at.c, xs1, xd1, ae1, q1)

// ---------------- k0: init + attention-dot constants ----------------
extern "C" __global__ __launch_bounds__(256)
void k0_init(float* __restrict__ ws,
             const float* __restrict__ att, const float* __restrict__ Wl,
             const float* __restrict__ Wr, const float* __restrict__ We,
             const float* __restrict__ bl, const float* __restrict__ br,
             float* __restrict__ out, int dense)
{
  int tid = blockIdx.x * 256 + threadIdx.x;
  int nt = gridDim.x * 256;
  if (dense) {
    unsigned* head = (unsigned*)(ws + WS_HEAD);
    for (int i = tid; i < 4 * NN; i += nt) head[i] = LEND;
    if (tid < 14) ws[WS_MOM + tid] = 0.f;
  } else {
    for (int i = tid; i < 4 * NN; i += nt) ws[WS_ACC + i] = 0.f;
    for (int i = tid; i < 256; i += nt) ws[WS_BNSUM + i] = 0.f;
  }
  for (int i = tid; i < NG * 128; i += nt) out[i] = 0.f;
  if (blockIdx.x == 0) {
    __shared__ float red[4][256];
    int t = threadIdx.x;                    // t = h*128 + d
    float a = att[t];
    red[0][t] = a * Wl[t];
    red[1][t] = a * Wr[t];
    red[2][t] = a * We[t];
    red[3][t] = a * (bl[t] + br[t]);
    __syncthreads();
    if (t < 8) {
      int k = t >> 1, h = t & 1;
      float s = 0.f;
      for (int d = 0; d < 128; ++d) s += red[k][h * 128 + d];
      ws[WS_C + h * 4 + k] = s;
    }
  }
}

// ---------------- ke: fused score+exp, 2-edge/thread, linked-list staging ----------------
extern "C" __global__ __launch_bounds__(256)
void ke_edge(const int* __restrict__ ei, const float* __restrict__ x,
             const float* __restrict__ eattr,
             const float* __restrict__ Wl, const float* __restrict__ Wr,
             const float* __restrict__ We, const float* __restrict__ bl,
             const float* __restrict__ br, const float* __restrict__ att,
             float* __restrict__ ws)
{
  SMEM_WEIGHTS_DECL
  SMEM_WEIGHTS_LOAD
  int base = (blockIdx.x * 256 + threadIdx.x) * 2;
  if (base >= NE) return;
  int2 s2 = *(const int2*)&ei[base];
  int2 d2 = *(const int2*)&ei[NE + base];
  float2 ae2 = *(const float2*)&eattr[base];
  float xs0 = x[s2.x], xs1 = x[s2.y];
  float xd0 = x[d2.x], xd1 = x[d2.y];
  float ae0 = ae2.x, ae1 = ae2.y;
  unsigned* head = (unsigned*)(ws + WS_HEAD);
  // random exchanges issued early; results consumed only at the very end.
  // chain slot = base&3 spreads consecutive edge pairs over the 4 chains/node.
  unsigned pv0 = atomicExch(&head[4 * d2.x + (base & 3)], (unsigned)(base + 0));
  unsigned pv1 = atomicExch(&head[4 * d2.y + ((base + 1) & 3)], (unsigned)(base + 1));
  float a00 = 0.f, a01 = 0.f;   // head0, edges 0..1
  float a10 = 0.f, a11 = 0.f;   // head1
#pragma unroll 4
  for (int j = 0; j < 128; j += 4) {
    float4 wl = *(const float4*)&sWl[j];
    float4 wr = *(const float4*)&sWr[j];
    float4 we = *(const float4*)&sWe[j];
    float4 bb = *(const float4*)&sB[j];
    float4 at = *(const float4*)&sAt[j];
    STEP2(x, a00, a01)
    STEP2(y, a00, a01)
    STEP2(z, a00, a01)
    STEP2(w, a00, a01)
  }
#pragma unroll 4
  for (int j = 128; j < 256; j += 4) {
    float4 wl = *(const float4*)&sWl[j];
    float4 wr = *(const float4*)&sWr[j];
    float4 we = *(const float4*)&sWe[j];
    float4 bb = *(const float4*)&sB[j];
    float4 at = *(const float4*)&sAt[j];
    STEP2(x, a10, a11)
    STEP2(y, a10, a11)
    STEP2(z, a10, a11)
    STEP2(w, a10, a11)
  }
  float4 c0 = *(const float4*)&ws[WS_C];
  float4 c1 = *(const float4*)&ws[WS_C + 4];
  float4* stage = (float4*)(ws + WS_STAGE);
  unsigned* prev = (unsigned*)(ws + WS_PREV);
  float s0, s1;
  SCORES(xs0, xd0, ae0, a00, a10, s0, s1)
  float e00 = __expf(s0), e01 = __expf(s1);
  SCORES(xs1, xd1, ae1, a01, a11, s0, s1)
  float e10 = __expf(s0), e11 = __expf(s1);
  stage[base + 0] = make_float4(e00, e01, e00 * xs0, e01 * xs0);
  stage[base + 1] = make_float4(e10, e11, e10 * xs1, e11 * xs1);
  *(uint2*)&prev[base] = make_uint2(pv0, pv1);
}

// ---------------- kfm: chain-walk gather + 14-moment BN reduction ----------------
// 2 threads per node (2 chains each); lane-pair shuffle combines halves.
extern "C" __global__ __launch_bounds__(256)
void kfm_gather(float* __restrict__ ws)
{
  const int t = threadIdx.x;
  int gid = blockIdx.x * 256 + t;          // 2 threads per node
  int n = gid >> 1;
  int half = gid & 1;
  float f1 = 0.f, f2 = 0.f, f3 = 0.f, f4 = 0.f;
  if (n < NN) {
    const unsigned* head = (const unsigned*)(ws + WS_HEAD);
    const unsigned* prev = (const unsigned*)(ws + WS_PREV);
    const float4* stage = (const float4*)(ws + WS_STAGE);
    uint2 p = *(const uint2*)&head[4 * n + 2 * half];
    float4 A0 = make_float4(0.f, 0.f, 0.f, 0.f);
    float4 A1 = A0;
    while ((p.x & p.y) != LEND) {
#define HOP(pc, Ac)                                                        \
      if (pc != LEND) {                                                    \
        float4 q = stage[pc];                                              \
        unsigned np = prev[pc];                                            \
        Ac.x += q.x; Ac.y += q.y; Ac.z += q.z; Ac.w += q.w;                \
        pc = np;                                                           \
      }
      HOP(p.x, A0) HOP(p.y, A1)
#undef HOP
    }
    float den0 = A0.x + A1.x;
    float den1 = A0.y + A1.y;
    float t10  = A0.z + A1.z;
    float t11  = A0.w + A1.w;
    den0 += __shfl_xor(den0, 1);
    den1 += __shfl_xor(den1, 1);
    t10  += __shfl_xor(t10, 1);
    t11  += __shfl_xor(t11, 1);
    if (half == 0) {
      *(float4*)&ws[WS_ACC + 4 * n] = make_float4(den0, den1, t10, t11);
      float r0 = 1.f / (den0 + 1e-16f);
      float r1 = 1.f / (den1 + 1e-16f);
      f1 = den0 * r0; f2 = t10 * r0; f3 = den1 * r1; f4 = t11 * r1;
    }
  }
  // moments: S1..S4, M11,M12,M13,M14,M22,M23,M24,M33,M34,M44
  float pm[14] = { f1, f2, f3, f4,
                   f1*f1, f1*f2, f1*f3, f1*f4,
                   f2*f2, f2*f3, f2*f4,
                   f3*f3, f3*f4, f4*f4 };
#pragma unroll
  for (int k = 0; k < 14; ++k) {
    float v = pm[k];
#pragma unroll
    for (int m = 32; m >= 1; m >>= 1) v += __shfl_xor(v, m);
    pm[k] = v;
  }
  __shared__ float smom[56];
  int wid = t >> 6, lane = t & 63;
  if (lane == 0) {
#pragma unroll
    for (int k = 0; k < 14; ++k) smom[wid * 14 + k] = pm[k];
  }
  __syncthreads();
  if (t < 14) {
    float s = smom[t] + smom[14 + t] + smom[28 + t] + smom[42 + t];
    if (s != 0.f) atomicAdd(&ws[WS_MOM + t], s);
  }
}

// ---------------- k4m: BN from moments + leaky_relu + graph pooling ----------------
extern "C" __global__ __launch_bounds__(256)
void k4m_pool(const int* __restrict__ batch,
              const float* __restrict__ Wl, const float* __restrict__ bl,
              const float* __restrict__ bias, const float* __restrict__ gamma,
              const float* __restrict__ beta,
              float* __restrict__ ws, float* __restrict__ out)
{
  const int CHUNK = (NN + (int)gridDim.x - 1) / (int)gridDim.x;
  int n0 = blockIdx.x * CHUNK;
  if (n0 >= NN) return;
  int n1 = n0 + CHUNK; if (n1 > NN) n1 = NN;
  int t = threadIdx.x;
  int d = t & 127;
  int row = t >> 7;
  float S1 = ws[WS_MOM + 0], S2 = ws[WS_MOM + 1];
  float S3 = ws[WS_MOM + 2], S4 = ws[WS_MOM + 3];
  float M11 = ws[WS_MOM + 4], M12 = ws[WS_MOM + 5], M13 = ws[WS_MOM + 6];
  float M14 = ws[WS_MOM + 7], M22 = ws[WS_MOM + 8], M23 = ws[WS_MOM + 9];
  float M24 = ws[WS_MOM + 10], M33 = ws[WS_MOM + 11], M34 = ws[WS_MOM + 12];
  float M44 = ws[WS_MOM + 13];
  float g1 = 0.5f * bl[d], g2 = 0.5f * Wl[d];
  float g3 = 0.5f * bl[128 + d], g4 = 0.5f * Wl[128 + d];
  float g5 = bias[d];
  const float invN = 1.f / (float)NN;
  float dotS = g1 * S1 + g2 * S2 + g3 * S3 + g4 * S4;
  float mean = (dotS + (float)NN * g5) * invN;
  float sumsq = g1*g1*M11 + g2*g2*M22 + g3*g3*M33 + g4*g4*M44
              + 2.f*(g1*g2*M12 + g1*g3*M13 + g1*g4*M14
                   + g2*g3*M23 + g2*g4*M24 + g3*g4*M34)
              + 2.f*g5*dotS + (float)NN*g5*g5;
  float var = fmaf(sumsq, invN, -mean * mean);
  float scale = gamma[d] * rsqrtf(var + 1e-5f);
  float shift = fmaf(-mean, scale, beta[d]);
  __shared__ float pool[4][128];
  for (int i = t; i < 512; i += 256) ((float*)pool)[i] = 0.f;
  __syncthreads();
  int g0 = batch[n0];
  for (int n = n0 + row; n < n1; n += 2) {
    float4 a = *(const float4*)&ws[WS_ACC + 4 * n];
    float r0 = 1.f / (a.x + 1e-16f);
    float r1 = 1.f / (a.y + 1e-16f);
    float o = g1 * (a.x * r0) + g2 * (a.z * r0)
            + g3 * (a.y * r1) + g4 * (a.w * r1) + g5;
    float v = fmaf(o, scale, shift);
    v = v > 0.f ? v : 0.01f * v;
    int g = batch[n];
    int slot = g - g0;                    // >= 0: batch is sorted
    if (slot < 4) atomicAdd(&pool[slot][d], v);
    else atomicAdd(&out[g * 128 + d], v);
  }
  __syncthreads();
  for (int i = t; i < 512; i += 256) {
    int slot = i >> 7, dd = i & 127;
    int g = g0 + slot;
    float v = pool[slot][dd];
    if (g < NG && v != 0.f) atomicAdd(&out[g * 128 + dd], v);
  }
}

// ==================== fallback path (small ws): direct atomics + BNSUM ====================
extern "C" __global__ __launch_bounds__(256)
void k12f(const int* __restrict__ ei, const float* __restrict__ x,
          const float* __restrict__ eattr,
          const float* __restrict__ Wl, const float* __restrict__ Wr,
          const float* __restrict__ We, const float* __restrict__ bl,
          const float* __restrict__ br, const float* __restrict__ att,
          float* __restrict__ ws)
{
  SMEM_WEIGHTS_DECL
  SMEM_WEIGHTS_LOAD
  int base = (blockIdx.x * 256 + threadIdx.x) * 4;
  if (base >= NE) return;
  SCORE_CORE
  SCORE_LOOPS
  float* acc = ws + WS_ACC;
  float s0, s1;
#define EPI2(xs_, xd_, ae_, accA, accB, dsti)                              \
  { SCORES(xs_, xd_, ae_, accA, accB, s0, s1)                              \
    float e0 = __expf(s0), e1 = __expf(s1);                                \
    float* a = &acc[4 * dsti];                                             \
    atomicAdd(a + 0, e0); atomicAdd(a + 1, e1);                            \
    atomicAdd(a + 2, e0 * xs_); atomicAdd(a + 3, e1 * xs_); }
  EPI2(xs0, xd0, ae0, a00, a10, dd4.x)
  EPI2(xs1, xd1, ae1, a01, a11, dd4.y)
  EPI2(xs2, xd2, ae2, a02, a12, dd4.z)
  EPI2(xs3, xd3, ae3, a03, a13, dd4.w)
#undef EPI2
}

__device__ __forceinline__ float node_out4(float4 a, float wl0, float wl1,
                                           float b0, float b1, float bs)
{
  float r0 = 1.f / (a.x + 1e-16f);
  float r1 = 1.f / (a.y + 1e-16f);
  return 0.5f * (fmaf(wl0, a.z * r0, b0 * (a.x * r0)) +
                 fmaf(wl1, a.w * r1, b1 * (a.y * r1))) + bs;
}

extern "C" __global__ __launch_bounds__(256)
void k3_stats(const float* __restrict__ Wl, const float* __restrict__ bl,
              const float* __restrict__ bias, float* __restrict__ ws)
{
  int d = threadIdx.x & 127;
  int row = threadIdx.x >> 7;
  float wl0 = Wl[d], wl1 = Wl[128 + d];
  float b0 = bl[d], b1 = bl[128 + d];
  float bs = bias[d];
  float sum = 0.f, sq = 0.f;
  for (int n = blockIdx.x * 2 + row; n < NN; n += gridDim.x * 2) {
    float4 a = *(const float4*)&ws[WS_ACC + 4 * n];
    float o = node_out4(a, wl0, wl1, b0, b1, bs);
    sum += o;
    sq = fmaf(o, o, sq);
  }
  __shared__ float l1[256], l2[256];
  l1[threadIdx.x] = sum; l2[threadIdx.x] = sq;
  __syncthreads();
  if (row == 0) {
    atomicAdd(&ws[WS_BNSUM + d], l1[d] + l1[128 + d]);
    atomicAdd(&ws[WS_BNSQ + d], l2[d] + l2[128 + d]);
  }
}

extern "C" __global__ __launch_bounds__(256)
void k4_pool(const int* __restrict__ batch,
             const float* __restrict__ Wl, const float* __restrict__ bl,
             const float* __restrict__ bias, const float* __restrict__ gamma,
             const float* __restrict__ beta,
             float* __restrict__ ws, float* __restrict__ out)
{
  const int CHUNK = (NN + (int)gridDim.x - 1) / (int)gridDim.x;
  int n0 = blockIdx.x * CHUNK;
  if (n0 >= NN) return;
  int n1 = n0 + CHUNK; if (n1 > NN) n1 = NN;
  int d = threadIdx.x & 127;
  int row = threadIdx.x >> 7;
  const float invN = 1.f / (float)NN;
  float mean = ws[WS_BNSUM + d] * invN;
  float var = fmaf(ws[WS_BNSQ + d], invN, -mean * mean);
  float scale = gamma[d] * rsqrtf(var + 1e-5f);
  float shift = fmaf(-mean, scale, beta[d]);
  float wl0 = Wl[d], wl1 = Wl[128 + d];
  float b0 = bl[d], b1 = bl[128 + d];
  float bs = bias[d];
  __shared__ float pool[4][128];
  for (int i = threadIdx.x; i < 512; i += 256) ((float*)pool)[i] = 0.f;
  __syncthreads();
  int g0 = batch[n0];
  for (int n = n0 + row; n < n1; n += 2) {
    float4 a = *(const float4*)&ws[WS_ACC + 4 * n];
    float o = node_out4(a, wl0, wl1, b0, b1, bs);
    float v = fmaf(o, scale, shift);
    v = v > 0.f ? v : 0.01f * v;
    int g = batch[n];
    int slot = g - g0;
    if (slot < 4) atomicAdd(&pool[slot][d], v);
    else atomicAdd(&out[g * 128 + d], v);
  }
  __syncthreads();
  for (int i = threadIdx.x; i < 512; i += 256) {
    int slot = i >> 7, dd = i & 127;
    int g = g0 + slot;
    float v = pool[slot][dd];
    if (g < NG && v != 0.f) atomicAdd(&out[g * 128 + dd], v);
  }
}

extern "C" void kernel_launch(void* const* d_in, const int* in_sizes, int n_in,
                              void* d_out, int out_size, void* d_ws, size_t ws_size,
                              hipStream_t stream) {
  const float* x     = (const float*)d_in[0];
  const int*   ei    = (const int*)d_in[1];
  const float* eattr = (const float*)d_in[2];
  const int*   batch = (const int*)d_in[3];
  const float* Wl    = (const float*)d_in[4];
  const float* bl    = (const float*)d_in[5];
  const float* Wr    = (const float*)d_in[6];
  const float* br    = (const float*)d_in[7];
  const float* We    = (const float*)d_in[8];
  const float* att   = (const float*)d_in[9];
  const float* bias  = (const float*)d_in[10];
  const float* gam   = (const float*)d_in[11];
  const float* bet   = (const float*)d_in[12];
  float* ws  = (float*)d_ws;
  float* out = (float*)d_out;

  const bool dense = (ws_size >= WS_NEED_BYTES);

  hipLaunchKernelGGL(k0_init, dim3(128), dim3(256), 0, stream,
                     ws, att, Wl, Wr, We, bl, br, out, dense ? 1 : 0);
  if (dense) {
    hipLaunchKernelGGL(ke_edge, dim3((NE / 2 + 255) / 256), dim3(256), 0, stream,
                       ei, x, eattr, Wl, Wr, We, bl, br, att, ws);
    hipLaunchKernelGGL(kfm_gather, dim3((2 * NN + 255) / 256), dim3(256), 0, stream, ws);
    hipLaunchKernelGGL(k4m_pool, dim3(256), dim3(256), 0, stream,
                       batch, Wl, bl, bias, gam, bet, ws, out);
  } else {
    hipLaunchKernelGGL(k12f, dim3((NE / 4 + 255) / 256), dim3(256), 0, stream,
                       ei, x, eattr, Wl, Wr, We, bl, br, att, ws);
    hipLaunchKernelGGL(k3_stats, dim3(256), dim3(256), 0, stream,
                       Wl, bl, bias, ws);
    hipLaunchKernelGGL(k4_pool, dim3(256), dim3(256), 0, stream,
                       batch, Wl, bl, bias, gam, bet, ws, out);
  }
}

// Round 11
// 184.944 us; speedup vs baseline: 3.1081x; 1.0080x over previous
//
#include <hip/hip_runtime.h>
#include <math.h>

#define NN 50000
#define NE 800000
#define NG 64

// ---------------- ws layout (float offsets) ----------------
#define WS_C     0                       // 8 floats: [h*4 + {att.Wl, att.Wr, att.We, att.B}]
#define WS_ACC   16                      // 4*NN floats: {den0,den1,t10,t11} per node (float4)
#define WS_BNSUM (WS_ACC + 4*NN)         // 128 (fallback path)
#define WS_BNSQ  (WS_BNSUM + 128)        // 128 (fallback path)
#define WS_MOM   WS_BNSUM                // dense path: 14 floats (overlaps BNSUM, paths exclusive)
#define WS_HEAD  (WS_BNSQ + 128)         // 4*NN u32 chain heads (0xFFFFFFFF = end)
#define WS_PREV  (WS_HEAD + 4*NN)        // NE u32 next-pointers
#define WS_STAGE (WS_PREV + NE)          // NE float4 = {e0, e1, e0*xs, e1*xs}
#define WS_END   (WS_STAGE + 4*NE)
#define WS_NEED_BYTES ((size_t)WS_END * 4 + 256)

#define LEND 0xFFFFFFFFu

static_assert(((WS_STAGE * 4) % 16) == 0, "stage 16B alignment");
static_assert(NE % 4 == 0, "edge unroll");

// ---------------- shared score machinery ----------------
#define STEP(wl_, wr_, we_, bb_, at_, xs_, xd_, ae_, acc_)                 \
  { float tt = fmaf(we_, ae_, bb_); tt = fmaf(wr_, xd_, tt);               \
    tt = fmaf(wl_, xs_, tt); acc_ = fmaf(fabsf(tt), at_, acc_); }

#define SMEM_WEIGHTS_DECL                                                  \
  __shared__ __align__(16) float sWl[256], sWr[256], sWe[256], sB[256], sAt[256];

#define SMEM_WEIGHTS_LOAD                                                  \
  { int t_ = threadIdx.x;                                                  \
    sWl[t_] = Wl[t_]; sWr[t_] = Wr[t_]; sWe[t_] = We[t_];                  \
    sB[t_] = bl[t_] + br[t_]; sAt[t_] = att[t_]; }                         \
  __syncthreads();

#define SCORES(xs_, xd_, ae_, accA, accB, out0, out1)                      \
  { float lin0 = fmaf(c0.x, xs_, fmaf(c0.y, xd_, fmaf(c0.z, ae_, c0.w))); \
    out0 = fmaf(0.4f, accA, 0.6f * lin0);                                  \
    float lin1 = fmaf(c1.x, xs_, fmaf(c1.y, xd_, fmaf(c1.z, ae_, c1.w))); \
    out1 = fmaf(0.4f, accB, 0.6f * lin1); }

// ---- 4-edge variants (fallback path) ----
#define STEP4(c, q0, q1, q2, q3)                                           \
  STEP(wl.c, wr.c, we.c, bb.c, at.c, xs0, xd0, ae0, q0)                    \
  STEP(wl.c, wr.c, we.c, bb.c, at.c, xs1, xd1, ae1, q1)                    \
  STEP(wl.c, wr.c, we.c, bb.c, at.c, xs2, xd2, ae2, q2)                    \
  STEP(wl.c, wr.c, we.c, bb.c, at.c, xs3, xd3, ae3, q3)

#define SCORE_CORE                                                         \
  int4 s4 = *(const int4*)&ei[base];                                       \
  int4 dd4 = *(const int4*)&ei[NE + base];                                 \
  float4 ae4 = *(const float4*)&eattr[base];                               \
  float xs0 = x[s4.x], xs1 = x[s4.y], xs2 = x[s4.z], xs3 = x[s4.w];        \
  float xd0 = x[dd4.x], xd1 = x[dd4.y], xd2 = x[dd4.z], xd3 = x[dd4.w];    \
  float ae0 = ae4.x, ae1 = ae4.y, ae2 = ae4.z, ae3 = ae4.w;

#define SCORE_LOOPS                                                        \
  float a00 = 0.f, a01 = 0.f, a02 = 0.f, a03 = 0.f;                        \
  float a10 = 0.f, a11 = 0.f, a12 = 0.f, a13 = 0.f;                        \
  _Pragma("unroll 2")                                                      \
  for (int j = 0; j < 128; j += 4) {                                       \
    float4 wl = *(const float4*)&sWl[j];                                   \
    float4 wr = *(const float4*)&sWr[j];                                   \
    float4 we = *(const float4*)&sWe[j];                                   \
    float4 bb = *(const float4*)&sB[j];                                    \
    float4 at = *(const float4*)&sAt[j];                                   \
    STEP4(x, a00, a01, a02, a03)                                           \
    STEP4(y, a00, a01, a02, a03)                                           \
    STEP4(z, a00, a01, a02, a03)                                           \
    STEP4(w, a00, a01, a02, a03)                                           \
  }                                                                        \
  _Pragma("unroll 2")                                                      \
  for (int j = 128; j < 256; j += 4) {                                     \
    float4 wl = *(const float4*)&sWl[j];                                   \
    float4 wr = *(const float4*)&sWr[j];                                   \
    float4 we = *(const float4*)&sWe[j];                                   \
    float4 bb = *(const float4*)&sB[j];                                    \
    float4 at = *(const float4*)&sAt[j];                                   \
    STEP4(x, a10, a11, a12, a13)                                           \
    STEP4(y, a10, a11, a12, a13)                                           \
    STEP4(z, a10, a11, a12, a13)                                           \
    STEP4(w, a10, a11, a12, a13)                                           \
  }                                                                        \
  float4 c0 = *(const float4*)&ws[WS_C];                                   \
  float4 c1 = *(const float4*)&ws[WS_C + 4];

// ---- 1-edge variant (dense ke path): two partial accumulators break the
//      per-d dependency chain; max waves for outstanding exchanges ----
#define STEP1(c, qa, qb)                                                   \
  STEP(wl.c, wr.c, we.c, bb.c, at.c, xs0, xd0, ae0, qa)

// ---------------- k0: init + attention-dot constants ----------------
extern "C" __global__ __launch_bounds__(256)
void k0_init(float* __restrict__ ws,
             const float* __restrict__ att, const float* __restrict__ Wl,
             const float* __restrict__ Wr, const float* __restrict__ We,
             const float* __restrict__ bl, const float* __restrict__ br,
             float* __restrict__ out, int dense)
{
  int tid = blockIdx.x * 256 + threadIdx.x;
  int nt = gridDim.x * 256;
  if (dense) {
    unsigned* head = (unsigned*)(ws + WS_HEAD);
    for (int i = tid; i < 4 * NN; i += nt) head[i] = LEND;
    if (tid < 14) ws[WS_MOM + tid] = 0.f;
  } else {
    for (int i = tid; i < 4 * NN; i += nt) ws[WS_ACC + i] = 0.f;
    for (int i = tid; i < 256; i += nt) ws[WS_BNSUM + i] = 0.f;
  }
  for (int i = tid; i < NG * 128; i += nt) out[i] = 0.f;
  if (blockIdx.x == 0) {
    __shared__ float red[4][256];
    int t = threadIdx.x;                    // t = h*128 + d
    float a = att[t];
    red[0][t] = a * Wl[t];
    red[1][t] = a * Wr[t];
    red[2][t] = a * We[t];
    red[3][t] = a * (bl[t] + br[t]);
    __syncthreads();
    if (t < 8) {
      int k = t >> 1, h = t & 1;
      float s = 0.f;
      for (int d = 0; d < 128; ++d) s += red[k][h * 128 + d];
      ws[WS_C + h * 4 + k] = s;
    }
  }
}

// ---------------- ke: fused score+exp, 1-edge/thread, linked-list staging ----------------
extern "C" __global__ __launch_bounds__(256)
void ke_edge(const int* __restrict__ ei, const float* __restrict__ x,
             const float* __restrict__ eattr,
             const float* __restrict__ Wl, const float* __restrict__ Wr,
             const float* __restrict__ We, const float* __restrict__ bl,
             const float* __restrict__ br, const float* __restrict__ att,
             float* __restrict__ ws)
{
  SMEM_WEIGHTS_DECL
  SMEM_WEIGHTS_LOAD
  int e = blockIdx.x * 256 + threadIdx.x;
  if (e >= NE) return;
  int src = ei[e];
  int dst = ei[NE + e];
  float ae0 = eattr[e];
  float xs0 = x[src];
  float xd0 = x[dst];
  unsigned* head = (unsigned*)(ws + WS_HEAD);
  // random exchange issued before the score loop; result consumed at the end
  unsigned pv = atomicExch(&head[4 * dst + (e & 3)], (unsigned)e);
  // two partial accumulators per head break the fma dependency chain
  float h0a = 0.f, h0b = 0.f, h1a = 0.f, h1b = 0.f;
#pragma unroll 4
  for (int j = 0; j < 128; j += 8) {
    {
      float4 wl = *(const float4*)&sWl[j];
      float4 wr = *(const float4*)&sWr[j];
      float4 we = *(const float4*)&sWe[j];
      float4 bb = *(const float4*)&sB[j];
      float4 at = *(const float4*)&sAt[j];
      STEP(wl.x, wr.x, we.x, bb.x, at.x, xs0, xd0, ae0, h0a)
      STEP(wl.y, wr.y, we.y, bb.y, at.y, xs0, xd0, ae0, h0b)
      STEP(wl.z, wr.z, we.z, bb.z, at.z, xs0, xd0, ae0, h0a)
      STEP(wl.w, wr.w, we.w, bb.w, at.w, xs0, xd0, ae0, h0b)
    }
    {
      float4 wl = *(const float4*)&sWl[j + 4];
      float4 wr = *(const float4*)&sWr[j + 4];
      float4 we = *(const float4*)&sWe[j + 4];
      float4 bb = *(const float4*)&sB[j + 4];
      float4 at = *(const float4*)&sAt[j + 4];
      STEP(wl.x, wr.x, we.x, bb.x, at.x, xs0, xd0, ae0, h0a)
      STEP(wl.y, wr.y, we.y, bb.y, at.y, xs0, xd0, ae0, h0b)
      STEP(wl.z, wr.z, we.z, bb.z, at.z, xs0, xd0, ae0, h0a)
      STEP(wl.w, wr.w, we.w, bb.w, at.w, xs0, xd0, ae0, h0b)
    }
  }
#pragma unroll 4
  for (int j = 128; j < 256; j += 8) {
    {
      float4 wl = *(const float4*)&sWl[j];
      float4 wr = *(const float4*)&sWr[j];
      float4 we = *(const float4*)&sWe[j];
      float4 bb = *(const float4*)&sB[j];
      float4 at = *(const float4*)&sAt[j];
      STEP(wl.x, wr.x, we.x, bb.x, at.x, xs0, xd0, ae0, h1a)
      STEP(wl.y, wr.y, we.y, bb.y, at.y, xs0, xd0, ae0, h1b)
      STEP(wl.z, wr.z, we.z, bb.z, at.z, xs0, xd0, ae0, h1a)
      STEP(wl.w, wr.w, we.w, bb.w, at.w, xs0, xd0, ae0, h1b)
    }
    {
      float4 wl = *(const float4*)&sWl[j + 4];
      float4 wr = *(const float4*)&sWr[j + 4];
      float4 we = *(const float4*)&sWe[j + 4];
      float4 bb = *(const float4*)&sB[j + 4];
      float4 at = *(const float4*)&sAt[j + 4];
      STEP(wl.x, wr.x, we.x, bb.x, at.x, xs0, xd0, ae0, h1a)
      STEP(wl.y, wr.y, we.y, bb.y, at.y, xs0, xd0, ae0, h1b)
      STEP(wl.z, wr.z, we.z, bb.z, at.z, xs0, xd0, ae0, h1a)
      STEP(wl.w, wr.w, we.w, bb.w, at.w, xs0, xd0, ae0, h1b)
    }
  }
  float a00 = h0a + h0b;
  float a10 = h1a + h1b;
  float4 c0 = *(const float4*)&ws[WS_C];
  float4 c1 = *(const float4*)&ws[WS_C + 4];
  float s0, s1;
  SCORES(xs0, xd0, ae0, a00, a10, s0, s1)
  float e0 = __expf(s0), e1 = __expf(s1);
  float4* stage = (float4*)(ws + WS_STAGE);
  unsigned* prev = (unsigned*)(ws + WS_PREV);
  stage[e] = make_float4(e0, e1, e0 * xs0, e1 * xs0);
  prev[e] = pv;
}

// ---------------- kfm: chain-walk gather + 14-moment BN reduction ----------------
// 2 threads per node (2 chains each); lane-pair shuffle combines halves.
extern "C" __global__ __launch_bounds__(256)
void kfm_gather(float* __restrict__ ws)
{
  const int t = threadIdx.x;
  int gid = blockIdx.x * 256 + t;          // 2 threads per node
  int n = gid >> 1;
  int half = gid & 1;
  float f1 = 0.f, f2 = 0.f, f3 = 0.f, f4 = 0.f;
  if (n < NN) {
    const unsigned* head = (const unsigned*)(ws + WS_HEAD);
    const unsigned* prev = (const unsigned*)(ws + WS_PREV);
    const float4* stage = (const float4*)(ws + WS_STAGE);
    uint2 p = *(const uint2*)&head[4 * n + 2 * half];
    float4 A0 = make_float4(0.f, 0.f, 0.f, 0.f);
    float4 A1 = A0;
    while ((p.x & p.y) != LEND) {
#define HOP(pc, Ac)                                                        \
      if (pc != LEND) {                                                    \
        float4 q = stage[pc];                                              \
        unsigned np = prev[pc];                                            \
        Ac.x += q.x; Ac.y += q.y; Ac.z += q.z; Ac.w += q.w;                \
        pc = np;                                                           \
      }
      HOP(p.x, A0) HOP(p.y, A1)
#undef HOP
    }
    float den0 = A0.x + A1.x;
    float den1 = A0.y + A1.y;
    float t10  = A0.z + A1.z;
    float t11  = A0.w + A1.w;
    den0 += __shfl_xor(den0, 1);
    den1 += __shfl_xor(den1, 1);
    t10  += __shfl_xor(t10, 1);
    t11  += __shfl_xor(t11, 1);
    if (half == 0) {
      *(float4*)&ws[WS_ACC + 4 * n] = make_float4(den0, den1, t10, t11);
      float r0 = 1.f / (den0 + 1e-16f);
      float r1 = 1.f / (den1 + 1e-16f);
      f1 = den0 * r0; f2 = t10 * r0; f3 = den1 * r1; f4 = t11 * r1;
    }
  }
  // moments: S1..S4, M11,M12,M13,M14,M22,M23,M24,M33,M34,M44
  float pm[14] = { f1, f2, f3, f4,
                   f1*f1, f1*f2, f1*f3, f1*f4,
                   f2*f2, f2*f3, f2*f4,
                   f3*f3, f3*f4, f4*f4 };
#pragma unroll
  for (int k = 0; k < 14; ++k) {
    float v = pm[k];
#pragma unroll
    for (int m = 32; m >= 1; m >>= 1) v += __shfl_xor(v, m);
    pm[k] = v;
  }
  __shared__ float smom[56];
  int wid = t >> 6, lane = t & 63;
  if (lane == 0) {
#pragma unroll
    for (int k = 0; k < 14; ++k) smom[wid * 14 + k] = pm[k];
  }
  __syncthreads();
  if (t < 14) {
    float s = smom[t] + smom[14 + t] + smom[28 + t] + smom[42 + t];
    if (s != 0.f) atomicAdd(&ws[WS_MOM + t], s);
  }
}

// ---------------- k4m: BN from moments + leaky_relu + graph pooling ----------------
extern "C" __global__ __launch_bounds__(256)
void k4m_pool(const int* __restrict__ batch,
              const float* __restrict__ Wl, const float* __restrict__ bl,
              const float* __restrict__ bias, const float* __restrict__ gamma,
              const float* __restrict__ beta,
              float* __restrict__ ws, float* __restrict__ out)
{
  const int CHUNK = (NN + (int)gridDim.x - 1) / (int)gridDim.x;
  int n0 = blockIdx.x * CHUNK;
  if (n0 >= NN) return;
  int n1 = n0 + CHUNK; if (n1 > NN) n1 = NN;
  int t = threadIdx.x;
  int d = t & 127;
  int row = t >> 7;
  float S1 = ws[WS_MOM + 0], S2 = ws[WS_MOM + 1];
  float S3 = ws[WS_MOM + 2], S4 = ws[WS_MOM + 3];
  float M11 = ws[WS_MOM + 4], M12 = ws[WS_MOM + 5], M13 = ws[WS_MOM + 6];
  float M14 = ws[WS_MOM + 7], M22 = ws[WS_MOM + 8], M23 = ws[WS_MOM + 9];
  float M24 = ws[WS_MOM + 10], M33 = ws[WS_MOM + 11], M34 = ws[WS_MOM + 12];
  float M44 = ws[WS_MOM + 13];
  float g1 = 0.5f * bl[d], g2 = 0.5f * Wl[d];
  float g3 = 0.5f * bl[128 + d], g4 = 0.5f * Wl[128 + d];
  float g5 = bias[d];
  const float invN = 1.f / (float)NN;
  float dotS = g1 * S1 + g2 * S2 + g3 * S3 + g4 * S4;
  float mean = (dotS + (float)NN * g5) * invN;
  float sumsq = g1*g1*M11 + g2*g2*M22 + g3*g3*M33 + g4*g4*M44
              + 2.f*(g1*g2*M12 + g1*g3*M13 + g1*g4*M14
                   + g2*g3*M23 + g2*g4*M24 + g3*g4*M34)
              + 2.f*g5*dotS + (float)NN*g5*g5;
  float var = fmaf(sumsq, invN, -mean * mean);
  float scale = gamma[d] * rsqrtf(var + 1e-5f);
  float shift = fmaf(-mean, scale, beta[d]);
  __shared__ float pool[4][128];
  for (int i = t; i < 512; i += 256) ((float*)pool)[i] = 0.f;
  __syncthreads();
  int g0 = batch[n0];
  for (int n = n0 + row; n < n1; n += 2) {
    float4 a = *(const float4*)&ws[WS_ACC + 4 * n];
    float r0 = 1.f / (a.x + 1e-16f);
    float r1 = 1.f / (a.y + 1e-16f);
    float o = g1 * (a.x * r0) + g2 * (a.z * r0)
            + g3 * (a.y * r1) + g4 * (a.w * r1) + g5;
    float v = fmaf(o, scale, shift);
    v = v > 0.f ? v : 0.01f * v;
    int g = batch[n];
    int slot = g - g0;                    // >= 0: batch is sorted
    if (slot < 4) atomicAdd(&pool[slot][d], v);
    else atomicAdd(&out[g * 128 + d], v);
  }
  __syncthreads();
  for (int i = t; i < 512; i += 256) {
    int slot = i >> 7, dd = i & 127;
    int g = g0 + slot;
    float v = pool[slot][dd];
    if (g < NG && v != 0.f) atomicAdd(&out[g * 128 + dd], v);
  }
}

// ==================== fallback path (small ws): direct atomics + BNSUM ====================
extern "C" __global__ __launch_bounds__(256)
void k12f(const int* __restrict__ ei, const float* __restrict__ x,
          const float* __restrict__ eattr,
          const float* __restrict__ Wl, const float* __restrict__ Wr,
          const float* __restrict__ We, const float* __restrict__ bl,
          const float* __restrict__ br, const float* __restrict__ att,
          float* __restrict__ ws)
{
  SMEM_WEIGHTS_DECL
  SMEM_WEIGHTS_LOAD
  int base = (blockIdx.x * 256 + threadIdx.x) * 4;
  if (base >= NE) return;
  SCORE_CORE
  SCORE_LOOPS
  float* acc = ws + WS_ACC;
  float s0, s1;
#define EPI2(xs_, xd_, ae_, accA, accB, dsti)                              \
  { SCORES(xs_, xd_, ae_, accA, accB, s0, s1)                              \
    float e0 = __expf(s0), e1 = __expf(s1);                                \
    float* a = &acc[4 * dsti];                                             \
    atomicAdd(a + 0, e0); atomicAdd(a + 1, e1);                            \
    atomicAdd(a + 2, e0 * xs_); atomicAdd(a + 3, e1 * xs_); }
  EPI2(xs0, xd0, ae0, a00, a10, dd4.x)
  EPI2(xs1, xd1, ae1, a01, a11, dd4.y)
  EPI2(xs2, xd2, ae2, a02, a12, dd4.z)
  EPI2(xs3, xd3, ae3, a03, a13, dd4.w)
#undef EPI2
}

__device__ __forceinline__ float node_out4(float4 a, float wl0, float wl1,
                                           float b0, float b1, float bs)
{
  float r0 = 1.f / (a.x + 1e-16f);
  float r1 = 1.f / (a.y + 1e-16f);
  return 0.5f * (fmaf(wl0, a.z * r0, b0 * (a.x * r0)) +
                 fmaf(wl1, a.w * r1, b1 * (a.y * r1))) + bs;
}

extern "C" __global__ __launch_bounds__(256)
void k3_stats(const float* __restrict__ Wl, const float* __restrict__ bl,
              const float* __restrict__ bias, float* __restrict__ ws)
{
  int d = threadIdx.x & 127;
  int row = threadIdx.x >> 7;
  float wl0 = Wl[d], wl1 = Wl[128 + d];
  float b0 = bl[d], b1 = bl[128 + d];
  float bs = bias[d];
  float sum = 0.f, sq = 0.f;
  for (int n = blockIdx.x * 2 + row; n < NN; n += gridDim.x * 2) {
    float4 a = *(const float4*)&ws[WS_ACC + 4 * n];
    float o = node_out4(a, wl0, wl1, b0, b1, bs);
    sum += o;
    sq = fmaf(o, o, sq);
  }
  __shared__ float l1[256], l2[256];
  l1[threadIdx.x] = sum; l2[threadIdx.x] = sq;
  __syncthreads();
  if (row == 0) {
    atomicAdd(&ws[WS_BNSUM + d], l1[d] + l1[128 + d]);
    atomicAdd(&ws[WS_BNSQ + d], l2[d] + l2[128 + d]);
  }
}

extern "C" __global__ __launch_bounds__(256)
void k4_pool(const int* __restrict__ batch,
             const float* __restrict__ Wl, const float* __restrict__ bl,
             const float* __restrict__ bias, const float* __restrict__ gamma,
             const float* __restrict__ beta,
             float* __restrict__ ws, float* __restrict__ out)
{
  const int CHUNK = (NN + (int)gridDim.x - 1) / (int)gridDim.x;
  int n0 = blockIdx.x * CHUNK;
  if (n0 >= NN) return;
  int n1 = n0 + CHUNK; if (n1 > NN) n1 = NN;
  int d = threadIdx.x & 127;
  int row = threadIdx.x >> 7;
  const float invN = 1.f / (float)NN;
  float mean = ws[WS_BNSUM + d] * invN;
  float var = fmaf(ws[WS_BNSQ + d], invN, -mean * mean);
  float scale = gamma[d] * rsqrtf(var + 1e-5f);
  float shift = fmaf(-mean, scale, beta[d]);
  float wl0 = Wl[d], wl1 = Wl[128 + d];
  float b0 = bl[d], b1 = bl[128 + d];
  float bs = bias[d];
  __shared__ float pool[4][128];
  for (int i = threadIdx.x; i < 512; i += 256) ((float*)pool)[i] = 0.f;
  __syncthreads();
  int g0 = batch[n0];
  for (int n = n0 + row; n < n1; n += 2) {
    float4 a = *(const float4*)&ws[WS_ACC + 4 * n];
    float o = node_out4(a, wl0, wl1, b0, b1, bs);
    float v = fmaf(o, scale, shift);
    v = v > 0.f ? v : 0.01f * v;
    int g = batch[n];
    int slot = g - g0;
    if (slot < 4) atomicAdd(&pool[slot][d], v);
    else atomicAdd(&out[g * 128 + d], v);
  }
  __syncthreads();
  for (int i = threadIdx.x; i < 512; i += 256) {
    int slot = i >> 7, dd = i & 127;
    int g = g0 + slot;
    float v = pool[slot][dd];
    if (g < NG && v != 0.f) atomicAdd(&out[g * 128 + dd], v);
  }
}

extern "C" void kernel_launch(void* const* d_in, const int* in_sizes, int n_in,
                              void* d_out, int out_size, void* d_ws, size_t ws_size,
                              hipStream_t stream) {
  const float* x     = (const float*)d_in[0];
  const int*   ei    = (const int*)d_in[1];
  const float* eattr = (const float*)d_in[2];
  const int*   batch = (const int*)d_in[3];
  const float* Wl    = (const float*)d_in[4];
  const float* bl    = (const float*)d_in[5];
  const float* Wr    = (const float*)d_in[6];
  const float* br    = (const float*)d_in[7];
  const float* We    = (const float*)d_in[8];
  const float* att   = (const float*)d_in[9];
  const float* bias  = (const float*)d_in[10];
  const float* gam   = (const float*)d_in[11];
  const float* bet   = (const float*)d_in[12];
  float* ws  = (float*)d_ws;
  float* out = (float*)d_out;

  const bool dense = (ws_size >= WS_NEED_BYTES);

  hipLaunchKernelGGL(k0_init, dim3(128), dim3(256), 0, stream,
                     ws, att, Wl, Wr, We, bl, br, out, dense ? 1 : 0);
  if (dense) {
    hipLaunchKernelGGL(ke_edge, dim3((NE + 255) / 256), dim3(256), 0, stream,
                       ei, x, eattr, Wl, Wr, We, bl, br, att, ws);
    hipLaunchKernelGGL(kfm_gather, dim3((2 * NN + 255) / 256), dim3(256), 0, stream, ws);
    hipLaunchKernelGGL(k4m_pool, dim3(256), dim3(256), 0, stream,
                       batch, Wl, bl, bias, gam, bet, ws, out);
  } else {
    hipLaunchKernelGGL(k12f, dim3((NE / 4 + 255) / 256), dim3(256), 0, stream,
                       ei, x, eattr, Wl, Wr, We, bl, br, att, ws);
    hipLaunchKernelGGL(k3_stats, dim3(256), dim3(256), 0, stream,
                       Wl, bl, bias, ws);
    hipLaunchKernelGGL(k4_pool, dim3(256), dim3(256), 0, stream,
                       batch, Wl, bl, bias, gam, bet, ws, out);
  }
}